// Round 1
// baseline (2729.751 us; speedup 1.0000x reference)
//
#include <hip/hip_runtime.h>
#include <math.h>

#define D_MODEL 2048
#define NH 16
#define KVG 4
#define DK 128
#define BB 2
#define SS 2048
#define ROWS (BB*SS)   // 4096
#define KVD (KVG*DK)   // 512

// ---------------- GEMM: C[M,N] = A[M,K] @ W[K,N] + bias ----------------
// 128x128 tile, BK=16, 256 threads, 8x8 per-thread microtile, fp32.
__global__ __launch_bounds__(256)
void gemm_bias_kernel(const float* __restrict__ A, const float* __restrict__ W,
                      const float* __restrict__ bias, float* __restrict__ C,
                      int M, int N, int K) {
  constexpr int BM = 128, BN = 128, BK = 16;
  __shared__ __align__(16) float As[BK][BM + 4];  // stored transposed: As[k][m]
  __shared__ __align__(16) float Bs[BK][BN + 4];  // Bs[k][n]
  const int tid = threadIdx.x;
  const int bm = blockIdx.y * BM;
  const int bn = blockIdx.x * BN;
  const int ti = (tid >> 4) * 8;   // row offset in tile
  const int tj = (tid & 15) * 8;   // col offset in tile

  float acc[8][8] = {};

  for (int k0 = 0; k0 < K; k0 += BK) {
    // Load A tile (128 rows x 16 k) transposed into As[k][m]
#pragma unroll
    for (int l = 0; l < 2; ++l) {
      int idx = tid * 2 + l;          // 0..511 float4s
      int r   = idx >> 2;             // 0..127
      int c4  = (idx & 3) << 2;       // 0,4,8,12
      const float4 v = *(const float4*)(A + (size_t)(bm + r) * K + (k0 + c4));
      As[c4 + 0][r] = v.x; As[c4 + 1][r] = v.y;
      As[c4 + 2][r] = v.z; As[c4 + 3][r] = v.w;
    }
    // Load W tile (16 k x 128 n) directly into Bs[k][n]
#pragma unroll
    for (int l = 0; l < 2; ++l) {
      int idx = tid * 2 + l;
      int r   = idx >> 5;             // 0..15
      int c4  = (idx & 31) << 2;      // 0..124
      *(float4*)&Bs[r][c4] = *(const float4*)(W + (size_t)(k0 + r) * N + (bn + c4));
    }
    __syncthreads();

#pragma unroll
    for (int kk = 0; kk < BK; ++kk) {
      float a[8], b[8];
      *(float4*)&a[0] = *(const float4*)&As[kk][ti];
      *(float4*)&a[4] = *(const float4*)&As[kk][ti + 4];
      *(float4*)&b[0] = *(const float4*)&Bs[kk][tj];
      *(float4*)&b[4] = *(const float4*)&Bs[kk][tj + 4];
#pragma unroll
      for (int m = 0; m < 8; ++m)
#pragma unroll
        for (int n = 0; n < 8; ++n)
          acc[m][n] = fmaf(a[m], b[n], acc[m][n]);
    }
    __syncthreads();
  }

#pragma unroll
  for (int m = 0; m < 8; ++m) {
    float* crow = C + (size_t)(bm + ti + m) * N + bn + tj;
#pragma unroll
    for (int n0 = 0; n0 < 8; n0 += 4) {
      float4 v;
      v.x = acc[m][n0 + 0] + bias[bn + tj + n0 + 0];
      v.y = acc[m][n0 + 1] + bias[bn + tj + n0 + 1];
      v.z = acc[m][n0 + 2] + bias[bn + tj + n0 + 2];
      v.w = acc[m][n0 + 3] + bias[bn + tj + n0 + 3];
      *(float4*)(crow + n0) = v;
    }
  }
}

// ---------------- Flash attention, fp32 ----------------
// grid: (S/64, B*NH); block 256.  QB=KB=64.
// thread (i = tid>>4, j = tid&15):
//   scores: rows 4i..4i+3, cols 4j..4j+3 (4x4)
//   PV/out: rows 4i..4i+3, d-cols 8j..8j+7 (4x8)
__global__ __launch_bounds__(256)
void attn_kernel(const float* __restrict__ Q, const float* __restrict__ Kb,
                 const float* __restrict__ Vb, float* __restrict__ AO) {
  constexpr int QB = 64, KB = 64;
  __shared__ __align__(16) float QsT[DK][QB + 4];  // QsT[d][r], scale folded
  __shared__ __align__(16) float KsT[DK][KB + 4];  // KsT[d][c]
  __shared__ __align__(16) float Vs[KB][DK];       // Vs[c][d]
  __shared__ __align__(16) float Ps[QB][KB + 4];   // Ps[r][c]

  const int tid = threadIdx.x;
  const int i = tid >> 4, j = tid & 15;
  const int qt = blockIdx.x;
  const int bh = blockIdx.y;
  const int b = bh >> 4, h = bh & 15;
  const int g = h >> 2;                    // rep = 4
  const float scale = 0.08838834764831845f;  // 1/sqrt(128)

  // Load Q tile transposed (fold in scale)
  const float* Qbase = Q + (size_t)(b * SS + qt * QB) * D_MODEL + h * DK;
#pragma unroll
  for (int l = 0; l < 8; ++l) {
    int idx = tid + l * 256;        // 0..2047 float4s
    int r   = idx >> 5;             // 0..63
    int d4  = (idx & 31) << 2;      // 0..124
    float4 v = *(const float4*)(Qbase + (size_t)r * D_MODEL + d4);
    QsT[d4 + 0][r] = v.x * scale; QsT[d4 + 1][r] = v.y * scale;
    QsT[d4 + 2][r] = v.z * scale; QsT[d4 + 3][r] = v.w * scale;
  }

  float o[4][8] = {};
  float mprev[4] = {-INFINITY, -INFINITY, -INFINITY, -INFINITY};
  float lsum[4] = {};

  const float* Kbase0 = Kb + (size_t)b * SS * KVD + (size_t)g * DK;
  const float* Vbase0 = Vb + (size_t)b * SS * KVD + (size_t)g * DK;

  for (int kt = 0; kt < SS / KB; ++kt) {
    __syncthreads();   // prev PV done (and first-iter QsT visible)
    // Load K tile transposed + V tile direct
#pragma unroll
    for (int l = 0; l < 8; ++l) {
      int idx = tid + l * 256;
      int r   = idx >> 5;            // key row in tile 0..63
      int d4  = (idx & 31) << 2;
      float4 kv = *(const float4*)(Kbase0 + (size_t)(kt * KB + r) * KVD + d4);
      KsT[d4 + 0][r] = kv.x; KsT[d4 + 1][r] = kv.y;
      KsT[d4 + 2][r] = kv.z; KsT[d4 + 3][r] = kv.w;
      float4 vv = *(const float4*)(Vbase0 + (size_t)(kt * KB + r) * KVD + d4);
      *(float4*)&Vs[r][d4] = vv;
    }
    __syncthreads();

    // scores 4x4 per thread
    float sc[4][4] = {};
    for (int k = 0; k < DK; ++k) {
      float a[4], kb[4];
      *(float4*)a  = *(const float4*)&QsT[k][4 * i];
      *(float4*)kb = *(const float4*)&KsT[k][4 * j];
#pragma unroll
      for (int m = 0; m < 4; ++m)
#pragma unroll
        for (int n = 0; n < 4; ++n)
          sc[m][n] = fmaf(a[m], kb[n], sc[m][n]);
    }

    // online softmax (per-row stats shared across the 16-lane row group)
    float alpha[4];
#pragma unroll
    for (int m = 0; m < 4; ++m) {
      float mt = fmaxf(fmaxf(sc[m][0], sc[m][1]), fmaxf(sc[m][2], sc[m][3]));
#pragma unroll
      for (int mask = 1; mask < 16; mask <<= 1)
        mt = fmaxf(mt, __shfl_xor(mt, mask));
      float mnew = fmaxf(mprev[m], mt);
      alpha[m] = expf(mprev[m] - mnew);
      float s = 0.f;
#pragma unroll
      for (int n = 0; n < 4; ++n) { sc[m][n] = expf(sc[m][n] - mnew); s += sc[m][n]; }
#pragma unroll
      for (int mask = 1; mask < 16; mask <<= 1)
        s += __shfl_xor(s, mask);
      lsum[m] = lsum[m] * alpha[m] + s;
      mprev[m] = mnew;
      *(float4*)&Ps[4 * i + m][4 * j] = *(float4*)sc[m];
    }
    __syncthreads();

    // PV: o[4][8] over this key tile
#pragma unroll
    for (int m = 0; m < 4; ++m)
#pragma unroll
      for (int n = 0; n < 8; ++n)
        o[m][n] *= alpha[m];

    for (int c0 = 0; c0 < KB; c0 += 4) {
      float p[4][4];
#pragma unroll
      for (int m = 0; m < 4; ++m)
        *(float4*)p[m] = *(const float4*)&Ps[4 * i + m][c0];
#pragma unroll
      for (int cc = 0; cc < 4; ++cc) {
        float vv[8];
        *(float4*)&vv[0] = *(const float4*)&Vs[c0 + cc][8 * j];
        *(float4*)&vv[4] = *(const float4*)&Vs[c0 + cc][8 * j + 4];
#pragma unroll
        for (int m = 0; m < 4; ++m)
#pragma unroll
          for (int n = 0; n < 8; ++n)
            o[m][n] = fmaf(p[m][cc], vv[n], o[m][n]);
      }
    }
  }

  // normalize + write attn output at [row][h*DK + 8j..]
#pragma unroll
  for (int m = 0; m < 4; ++m) {
    float rl = 1.0f / lsum[m];
    float* orow = AO + (size_t)(b * SS + qt * QB + 4 * i + m) * D_MODEL + h * DK + 8 * j;
    float4 v0, v1;
    v0.x = o[m][0] * rl; v0.y = o[m][1] * rl; v0.z = o[m][2] * rl; v0.w = o[m][3] * rl;
    v1.x = o[m][4] * rl; v1.y = o[m][5] * rl; v1.z = o[m][6] * rl; v1.w = o[m][7] * rl;
    *(float4*)orow       = v0;
    *(float4*)(orow + 4) = v1;
  }
}

extern "C" void kernel_launch(void* const* d_in, const int* in_sizes, int n_in,
                              void* d_out, int out_size, void* d_ws, size_t ws_size,
                              hipStream_t stream) {
  const float* x  = (const float*)d_in[0];
  const float* Wq = (const float*)d_in[1];
  const float* bq = (const float*)d_in[2];
  const float* Wk = (const float*)d_in[3];
  const float* bk = (const float*)d_in[4];
  const float* Wv = (const float*)d_in[5];
  const float* bv = (const float*)d_in[6];
  const float* Wo = (const float*)d_in[7];
  const float* bo = (const float*)d_in[8];
  float* out = (float*)d_out;

  float* Qb = (float*)d_ws;                       // [4096, 2048]
  float* Kb = Qb + (size_t)ROWS * D_MODEL;        // [4096, 512]
  float* Vb = Kb + (size_t)ROWS * KVD;            // [4096, 512]
  float* AO = Vb + (size_t)ROWS * KVD;            // [4096, 2048]

  dim3 blk(256);
  gemm_bias_kernel<<<dim3(D_MODEL / 128, ROWS / 128), blk, 0, stream>>>(
      x, Wq, bq, Qb, ROWS, D_MODEL, D_MODEL);
  gemm_bias_kernel<<<dim3(KVD / 128, ROWS / 128), blk, 0, stream>>>(
      x, Wk, bk, Kb, ROWS, KVD, D_MODEL);
  gemm_bias_kernel<<<dim3(KVD / 128, ROWS / 128), blk, 0, stream>>>(
      x, Wv, bv, Vb, ROWS, KVD, D_MODEL);
  attn_kernel<<<dim3(SS / 64, BB * NH), blk, 0, stream>>>(Qb, Kb, Vb, AO);
  gemm_bias_kernel<<<dim3(D_MODEL / 128, ROWS / 128), blk, 0, stream>>>(
      AO, Wo, bo, out, ROWS, D_MODEL, D_MODEL);
}

// Round 2
// 436.252 us; speedup vs baseline: 6.2573x; 6.2573x over previous
//
#include <hip/hip_runtime.h>
#include <math.h>
#include <stdint.h>

#define D_MODEL 2048
#define SS 2048
#define BB 2
#define ROWS (BB*SS)      // 4096
#define NQKV 3072
#define AO_W 4096

typedef __attribute__((ext_vector_type(8))) short bf16x8;
typedef __attribute__((ext_vector_type(4))) float f32x4;
typedef __attribute__((ext_vector_type(8))) unsigned short ushort8v;
typedef __attribute__((ext_vector_type(4))) unsigned short ushort4v;

__device__ __forceinline__ unsigned short f2bf(float f) {
  uint32_t u = __builtin_bit_cast(uint32_t, f);
  return (unsigned short)((u + 0x7FFFu + ((u >> 16) & 1u)) >> 16);
}
__device__ __forceinline__ float bf2f(unsigned short h) {
  uint32_t u = ((uint32_t)h) << 16;
  return __builtin_bit_cast(float, u);
}

#define MFMA16x16x32 __builtin_amdgcn_mfma_f32_16x16x32_bf16

#define GLOAD16(gsrc, ldst) \
  __builtin_amdgcn_global_load_lds((const __attribute__((address_space(1))) void*)(gsrc), \
      (__attribute__((address_space(3))) void*)(ldst), 16, 0, 0)

// ---------------- fp32 -> bf16 convert (x) ----------------
__global__ __launch_bounds__(256)
void conv_x(const float* __restrict__ x, unsigned short* __restrict__ xb) {
  size_t i = ((size_t)blockIdx.x * 256 + threadIdx.x) * 8;
  float4 v0 = *(const float4*)(x + i);
  float4 v1 = *(const float4*)(x + i + 4);
  ushort8v o;
  o[0]=f2bf(v0.x); o[1]=f2bf(v0.y); o[2]=f2bf(v0.z); o[3]=f2bf(v0.w);
  o[4]=f2bf(v1.x); o[5]=f2bf(v1.y); o[6]=f2bf(v1.z); o[7]=f2bf(v1.w);
  *(ushort8v*)(xb + i) = o;
}

// ---------------- pack Wq|Wk|Wv transposed -> WT[3072][2048] bf16 ----------------
__global__ __launch_bounds__(256)
void pack_wqkvT(const float* __restrict__ Wq, const float* __restrict__ Wk,
                const float* __restrict__ Wv, unsigned short* __restrict__ WT) {
  __shared__ float T[32][33];
  const int k0 = blockIdx.x * 32, n0 = blockIdx.y * 32;
  const int tid = threadIdx.x;
  const float* W; int nbase, stride;
  if (n0 < 2048)      { W = Wq; nbase = n0;        stride = 2048; }
  else if (n0 < 2560) { W = Wk; nbase = n0 - 2048; stride = 512;  }
  else                { W = Wv; nbase = n0 - 2560; stride = 512;  }
  int r = tid >> 3, c = (tid & 7) * 4;
  float4 v = *(const float4*)(W + (size_t)(k0 + r) * stride + nbase + c);
  T[c + 0][r] = v.x; T[c + 1][r] = v.y; T[c + 2][r] = v.z; T[c + 3][r] = v.w;
  __syncthreads();
  ushort4v o;
  o[0]=f2bf(T[r][c]); o[1]=f2bf(T[r][c+1]); o[2]=f2bf(T[r][c+2]); o[3]=f2bf(T[r][c+3]);
  *(ushort4v*)(WT + (size_t)(n0 + r) * 2048 + k0 + c) = o;
}

// ---------------- pack Wo transposed hi|lo -> WoT[2048][4096] bf16 ----------------
__global__ __launch_bounds__(256)
void pack_woT(const float* __restrict__ Wo, unsigned short* __restrict__ WoT) {
  __shared__ float T[32][33];
  const int k0 = blockIdx.x * 32, n0 = blockIdx.y * 32;
  const int tid = threadIdx.x;
  int r = tid >> 3, c = (tid & 7) * 4;
  float4 v = *(const float4*)(Wo + (size_t)(k0 + r) * 2048 + n0 + c);
  T[c+0][r]=v.x; T[c+1][r]=v.y; T[c+2][r]=v.z; T[c+3][r]=v.w;
  __syncthreads();
  ushort4v oh, ol;
#pragma unroll
  for (int j = 0; j < 4; ++j) {
    float f = T[r][c + j];
    unsigned short hb = f2bf(f);
    oh[j] = hb;
    ol[j] = f2bf(f - bf2f(hb));
  }
  *(ushort4v*)(WoT + (size_t)(n0 + r) * 4096 + k0 + c) = oh;
  *(ushort4v*)(WoT + (size_t)(n0 + r) * 4096 + 2048 + k0 + c) = ol;
}

__global__ void pack_bias(const float* __restrict__ bq, const float* __restrict__ bk,
                          const float* __restrict__ bv, float* __restrict__ bqkv) {
  int i = blockIdx.x * 256 + threadIdx.x;
  if (i >= 3072) return;
  bqkv[i] = i < 2048 ? bq[i] : (i < 2560 ? bk[i - 2048] : bv[i - 2560]);
}

// ---------------- bf16 MFMA GEMM: C = A[M][AW-slice] @ BT[N][BW-slice]^T + bias --------
// 128x128 tile, BK=64, 256 threads (4 waves, 2x2), 4x4 16x16 acc blocks per wave.
// SEGS=1: plain K=2048. SEGS=3: hi/lo split (A=[hi|lo] 4096 wide, BT=[hi|lo] 4096 wide):
//   hi@hi + hi@lo + lo@hi.
template<int SEGS, bool BF16OUT>
__global__ __launch_bounds__(256)
void gemm_bf16(const unsigned short* __restrict__ A,
               const unsigned short* __restrict__ BT,
               const float* __restrict__ bias,
               void* __restrict__ Cv,
               int N, int AW, int BW) {
  __shared__ unsigned short As[128 * 64];
  __shared__ unsigned short Bs[128 * 64];
  const int tid = threadIdx.x;
  const int w = tid >> 6, l = tid & 63;
  const int bm = blockIdx.y * 128, bn = blockIdx.x * 128;
  const int mbase = (w & 1) * 64, nbase = (w >> 1) * 64;

  f32x4 acc[4][4] = {};

  const int aSeg[3] = {0, 0, 2048};
  const int bSeg[3] = {0, 2048, 0};

  for (int s = 0; s < SEGS; ++s) {
    for (int t = 0; t < 32; ++t) {
      const int ka = aSeg[s] + t * 64;
      const int kb = bSeg[s] + t * 64;
      __syncthreads();
#pragma unroll
      for (int i = 0; i < 4; ++i) {
        int r0 = w * 32 + i * 8;
        int row = r0 + (l >> 3);
        int gr = l & 7;
        const unsigned short* srcA = A + (size_t)(bm + row) * AW + ka + ((gr ^ (row & 7)) << 3);
        GLOAD16(srcA, As + r0 * 64);
        const unsigned short* srcB = BT + (size_t)(bn + row) * BW + kb + ((gr ^ (row & 7)) << 3);
        GLOAD16(srcB, Bs + r0 * 64);
      }
      __syncthreads();
#pragma unroll
      for (int ks = 0; ks < 2; ++ks) {
        bf16x8 af[4], bfr[4];
#pragma unroll
        for (int mb = 0; mb < 4; ++mb) {
          int row = mbase + mb * 16 + (l & 15);
          int g = ks * 4 + (l >> 4);
          af[mb] = *(const bf16x8*)((const char*)As + row * 128 + ((g ^ (row & 7)) << 4));
        }
#pragma unroll
        for (int nb = 0; nb < 4; ++nb) {
          int row = nbase + nb * 16 + (l & 15);
          int g = ks * 4 + (l >> 4);
          bfr[nb] = *(const bf16x8*)((const char*)Bs + row * 128 + ((g ^ (row & 7)) << 4));
        }
#pragma unroll
        for (int mb = 0; mb < 4; ++mb)
#pragma unroll
          for (int nb = 0; nb < 4; ++nb)
            acc[mb][nb] = MFMA16x16x32(af[mb], bfr[nb], acc[mb][nb], 0, 0, 0);
      }
    }
  }
#pragma unroll
  for (int mb = 0; mb < 4; ++mb) {
#pragma unroll
    for (int nb = 0; nb < 4; ++nb) {
#pragma unroll
      for (int r = 0; r < 4; ++r) {
        int row = bm + mbase + mb * 16 + (l >> 4) * 4 + r;
        int col = bn + nbase + nb * 16 + (l & 15);
        float v = acc[mb][nb][r] + bias[col];
        if (BF16OUT) ((unsigned short*)Cv)[(size_t)row * N + col] = f2bf(v);
        else         ((float*)Cv)[(size_t)row * N + col] = v;
      }
    }
  }
}

// ---------------- MFMA flash attention ----------------
// grid (S/64, B*16). 4 waves; wave w owns q-rows [w*16, w*16+16).
// K tile 64x128 in LDS (gload_lds, XOR-swizzled), V transposed 128x64 (reg-staged,
// swizzled), P wave-private 16x64 via LDS. Softmax fp32, online (m,l per row).
__global__ __launch_bounds__(256)
void attn_mfma(const unsigned short* __restrict__ QKV,
               unsigned short* __restrict__ AOp) {
  __shared__ unsigned short Ks[64 * 128];
  __shared__ unsigned short VsT[128 * 64];
  __shared__ unsigned short Ps[4 * 16 * 64];
  const int tid = threadIdx.x;
  const int w = tid >> 6, l = tid & 63;
  const int qt = blockIdx.x;
  const int bh = blockIdx.y;
  const int b = bh >> 4, h = bh & 15, g = h >> 2;
  const float scale = 0.08838834764831845f;  // 1/sqrt(128)

  bf16x8 qf[4];
  {
    const int qrow = b * SS + qt * 64 + w * 16 + (l & 15);
    const unsigned short* qp = QKV + (size_t)qrow * NQKV + h * 128 + ((l >> 4) << 3);
#pragma unroll
    for (int ks = 0; ks < 4; ++ks) qf[ks] = *(const bf16x8*)(qp + ks * 32);
  }

  f32x4 oacc[8] = {};
  float mrow[4] = {-1e30f, -1e30f, -1e30f, -1e30f};
  float lrow[4] = {0.f, 0.f, 0.f, 0.f};

  const size_t kvbase = (size_t)b * SS * NQKV;

  for (int kt = 0; kt < SS / 64; ++kt) {
    __syncthreads();
    // stage K tile: wave w stages rows w*16..w*16+15 (4 gload_lds each)
#pragma unroll
    for (int i = 0; i < 4; ++i) {
      int r0 = w * 16 + i * 4;
      int row = r0 + (l >> 4);
      int gr = l & 15;
      const unsigned short* src = QKV + kvbase + (size_t)(kt * 64 + row) * NQKV
                                  + 2048 + g * 128 + ((gr ^ (row & 7)) << 3);
      GLOAD16(src, Ks + r0 * 128);
    }
    // stage V transposed: thread handles key pair (2kp,2kp+1), 16 d-values
    {
      int kp = tid & 31;
      int dc = tid >> 5;  // 0..7
      const unsigned short* v0p = QKV + kvbase + (size_t)(kt * 64 + kp * 2) * NQKV
                                  + 2560 + g * 128 + dc * 16;
      const unsigned short* v1p = v0p + NQKV;
      bf16x8 a0 = *(const bf16x8*)(v0p);
      bf16x8 a1 = *(const bf16x8*)(v0p + 8);
      bf16x8 b0 = *(const bf16x8*)(v1p);
      bf16x8 b1 = *(const bf16x8*)(v1p + 8);
#pragma unroll
      for (int jj = 0; jj < 16; ++jj) {
        int d = dc * 16 + jj;
        unsigned short e0 = (unsigned short)(jj < 8 ? a0[jj] : a1[jj - 8]);
        unsigned short e1 = (unsigned short)(jj < 8 ? b0[jj] : b1[jj - 8]);
        uint32_t val = (uint32_t)e0 | ((uint32_t)e1 << 16);
        int byte = (d * 128 + kp * 4) ^ ((d & 7) << 4);
        *(uint32_t*)((char*)VsT + byte) = val;
      }
    }
    __syncthreads();

    // QK^T: sacc[nb] = Q(16x128) @ K^T(128x16) for key block nb
    f32x4 sacc[4] = {};
#pragma unroll
    for (int ks = 0; ks < 4; ++ks) {
#pragma unroll
      for (int nb = 0; nb < 4; ++nb) {
        int key = nb * 16 + (l & 15);
        int grn = ks * 4 + (l >> 4);
        bf16x8 kf = *(const bf16x8*)((const char*)Ks + key * 256 + ((grn ^ (key & 7)) << 4));
        sacc[nb] = MFMA16x16x32(qf[ks], kf, sacc[nb], 0, 0, 0);
      }
    }

    // online softmax; P -> LDS (bf16)
    float alpha[4];
    unsigned short* pw = (unsigned short*)((char*)Ps + w * 2048);
#pragma unroll
    for (int r = 0; r < 4; ++r) {
      float s0 = sacc[0][r] * scale, s1 = sacc[1][r] * scale,
            s2 = sacc[2][r] * scale, s3 = sacc[3][r] * scale;
      float mx = fmaxf(fmaxf(s0, s1), fmaxf(s2, s3));
#pragma unroll
      for (int msk = 1; msk < 16; msk <<= 1) mx = fmaxf(mx, __shfl_xor(mx, msk, 64));
      float mnew = fmaxf(mrow[r], mx);
      alpha[r] = __expf(mrow[r] - mnew);
      float e0 = __expf(s0 - mnew), e1 = __expf(s1 - mnew),
            e2 = __expf(s2 - mnew), e3 = __expf(s3 - mnew);
      float sum = e0 + e1 + e2 + e3;
#pragma unroll
      for (int msk = 1; msk < 16; msk <<= 1) sum += __shfl_xor(sum, msk, 64);
      lrow[r] = lrow[r] * alpha[r] + sum;
      mrow[r] = mnew;
      int prow = (l >> 4) * 4 + r;
      int base = prow * 128 + (l & 15) * 2;
      int swz = (prow & 7) << 4;
      *(unsigned short*)((char*)pw + ((base +  0) ^ swz)) = f2bf(e0);
      *(unsigned short*)((char*)pw + ((base + 32) ^ swz)) = f2bf(e1);
      *(unsigned short*)((char*)pw + ((base + 64) ^ swz)) = f2bf(e2);
      *(unsigned short*)((char*)pw + ((base + 96) ^ swz)) = f2bf(e3);
    }

    // rescale O accumulators
#pragma unroll
    for (int nb = 0; nb < 8; ++nb)
#pragma unroll
      for (int r = 0; r < 4; ++r) oacc[nb][r] *= alpha[r];

    // PV: O(16x128) += P(16x64) @ V(64x128)
#pragma unroll
    for (int ks = 0; ks < 2; ++ks) {
      int prow = l & 15;
      int grn = ks * 4 + (l >> 4);
      bf16x8 pf = *(const bf16x8*)((const char*)Ps + w * 2048 + prow * 128
                                   + ((grn ^ (prow & 7)) << 4));
#pragma unroll
      for (int nb = 0; nb < 8; ++nb) {
        int d = nb * 16 + (l & 15);
        bf16x8 vf = *(const bf16x8*)((const char*)VsT + d * 128
                                     + ((grn ^ (d & 7)) << 4));
        oacc[nb] = MFMA16x16x32(pf, vf, oacc[nb], 0, 0, 0);
      }
    }
  }

  // epilogue: AO = [hi(2048) | lo(2048)] bf16
  const int rowb = b * SS + qt * 64 + w * 16 + (l >> 4) * 4;
#pragma unroll
  for (int r = 0; r < 4; ++r) {
    float rl = 1.0f / lrow[r];
    unsigned short* outp = AOp + (size_t)(rowb + r) * AO_W + h * 128 + (l & 15);
#pragma unroll
    for (int nb = 0; nb < 8; ++nb) {
      float v = oacc[nb][r] * rl;
      unsigned short hi = f2bf(v);
      unsigned short lo = f2bf(v - bf2f(hi));
      outp[nb * 16] = hi;
      outp[nb * 16 + 2048] = lo;
    }
  }
}

extern "C" void kernel_launch(void* const* d_in, const int* in_sizes, int n_in,
                              void* d_out, int out_size, void* d_ws, size_t ws_size,
                              hipStream_t stream) {
  const float* x  = (const float*)d_in[0];
  const float* Wq = (const float*)d_in[1];
  const float* bq = (const float*)d_in[2];
  const float* Wk = (const float*)d_in[3];
  const float* bk = (const float*)d_in[4];
  const float* Wv = (const float*)d_in[5];
  const float* bv = (const float*)d_in[6];
  const float* Wo = (const float*)d_in[7];
  const float* bo = (const float*)d_in[8];
  float* out = (float*)d_out;

  char* ws = (char*)d_ws;
  // layout (bytes): x_bf [0,16.8M) ; WqkvT [16.8M,29.4M) ; AO [0,33.6M) reuses both
  // (dead after QKV GEMM) ; bqkv @34M ; WoT [35M,51.8M) ; QKV [52M,77.2M)
  unsigned short* x_bf  = (unsigned short*)(ws);
  unsigned short* WqkvT = (unsigned short*)(ws + 16777216);
  unsigned short* AO    = (unsigned short*)(ws);
  float*          bqkv  = (float*)(ws + 35651584);
  unsigned short* WoT   = (unsigned short*)(ws + 36700160);
  unsigned short* QKV   = (unsigned short*)(ws + 54525952);

  conv_x<<<4096, 256, 0, stream>>>(x, x_bf);
  pack_wqkvT<<<dim3(64, 96), 256, 0, stream>>>(Wq, Wk, Wv, WqkvT);
  pack_bias<<<12, 256, 0, stream>>>(bq, bk, bv, bqkv);
  pack_woT<<<dim3(64, 64), 256, 0, stream>>>(Wo, WoT);
  gemm_bf16<1, true><<<dim3(24, 32), 256, 0, stream>>>(x_bf, WqkvT, bqkv, QKV,
                                                        NQKV, 2048, 2048);
  attn_mfma<<<dim3(32, 32), 256, 0, stream>>>(QKV, AO);
  gemm_bf16<3, false><<<dim3(16, 32), 256, 0, stream>>>(AO, WoT, bo, out,
                                                         2048, 4096, 4096);
}

// Round 3
// 354.021 us; speedup vs baseline: 7.7107x; 1.2323x over previous
//
#include <hip/hip_runtime.h>
#include <math.h>
#include <stdint.h>

#define D_MODEL 2048
#define SS 2048
#define BB 2
#define ROWS (BB*SS)      // 4096
#define NQKV 3072
#define AO_W 4096

typedef __attribute__((ext_vector_type(8))) short bf16x8;
typedef __attribute__((ext_vector_type(4))) float f32x4;
typedef __attribute__((ext_vector_type(8))) unsigned short ushort8v;
typedef __attribute__((ext_vector_type(4))) unsigned short ushort4v;

__device__ __forceinline__ unsigned short f2bf(float f) {
  uint32_t u = __builtin_bit_cast(uint32_t, f);
  return (unsigned short)((u + 0x7FFFu + ((u >> 16) & 1u)) >> 16);
}
__device__ __forceinline__ float bf2f(unsigned short h) {
  uint32_t u = ((uint32_t)h) << 16;
  return __builtin_bit_cast(float, u);
}

#define MFMA16x16x32 __builtin_amdgcn_mfma_f32_16x16x32_bf16

#define GLOAD16(gsrc, ldst) \
  __builtin_amdgcn_global_load_lds((const __attribute__((address_space(1))) void*)(gsrc), \
      (__attribute__((address_space(3))) void*)(ldst), 16, 0, 0)

// ---------------- fp32 -> bf16 convert (x) ----------------
__global__ __launch_bounds__(256)
void conv_x(const float* __restrict__ x, unsigned short* __restrict__ xb) {
  size_t i = ((size_t)blockIdx.x * 256 + threadIdx.x) * 8;
  float4 v0 = *(const float4*)(x + i);
  float4 v1 = *(const float4*)(x + i + 4);
  ushort8v o;
  o[0]=f2bf(v0.x); o[1]=f2bf(v0.y); o[2]=f2bf(v0.z); o[3]=f2bf(v0.w);
  o[4]=f2bf(v1.x); o[5]=f2bf(v1.y); o[6]=f2bf(v1.z); o[7]=f2bf(v1.w);
  *(ushort8v*)(xb + i) = o;
}

// ---------------- pack Wq|Wk|Wv transposed -> WT[3072][2048] bf16 ----------------
__global__ __launch_bounds__(256)
void pack_wqkvT(const float* __restrict__ Wq, const float* __restrict__ Wk,
                const float* __restrict__ Wv, unsigned short* __restrict__ WT) {
  __shared__ float T[32][33];
  const int k0 = blockIdx.x * 32, n0 = blockIdx.y * 32;
  const int tid = threadIdx.x;
  const float* W; int nbase, stride;
  if (n0 < 2048)      { W = Wq; nbase = n0;        stride = 2048; }
  else if (n0 < 2560) { W = Wk; nbase = n0 - 2048; stride = 512;  }
  else                { W = Wv; nbase = n0 - 2560; stride = 512;  }
  int r = tid >> 3, c = (tid & 7) * 4;
  float4 v = *(const float4*)(W + (size_t)(k0 + r) * stride + nbase + c);
  T[c + 0][r] = v.x; T[c + 1][r] = v.y; T[c + 2][r] = v.z; T[c + 3][r] = v.w;
  __syncthreads();
  ushort4v o;
  o[0]=f2bf(T[r][c]); o[1]=f2bf(T[r][c+1]); o[2]=f2bf(T[r][c+2]); o[3]=f2bf(T[r][c+3]);
  *(ushort4v*)(WT + (size_t)(n0 + r) * 2048 + k0 + c) = o;
}

// ---------------- pack Wo transposed hi|lo -> WoT[2048][4096] bf16 ----------------
__global__ __launch_bounds__(256)
void pack_woT(const float* __restrict__ Wo, unsigned short* __restrict__ WoT) {
  __shared__ float T[32][33];
  const int k0 = blockIdx.x * 32, n0 = blockIdx.y * 32;
  const int tid = threadIdx.x;
  int r = tid >> 3, c = (tid & 7) * 4;
  float4 v = *(const float4*)(Wo + (size_t)(k0 + r) * 2048 + n0 + c);
  T[c+0][r]=v.x; T[c+1][r]=v.y; T[c+2][r]=v.z; T[c+3][r]=v.w;
  __syncthreads();
  ushort4v oh, ol;
#pragma unroll
  for (int j = 0; j < 4; ++j) {
    float f = T[r][c + j];
    unsigned short hb = f2bf(f);
    oh[j] = hb;
    ol[j] = f2bf(f - bf2f(hb));
  }
  *(ushort4v*)(WoT + (size_t)(n0 + r) * 4096 + k0 + c) = oh;
  *(ushort4v*)(WoT + (size_t)(n0 + r) * 4096 + 2048 + k0 + c) = ol;
}

__global__ void pack_bias(const float* __restrict__ bq, const float* __restrict__ bk,
                          const float* __restrict__ bv, float* __restrict__ bqkv) {
  int i = blockIdx.x * 256 + threadIdx.x;
  if (i >= 3072) return;
  bqkv[i] = i < 2048 ? bq[i] : (i < 2560 ? bk[i - 2048] : bv[i - 2560]);
}

// ---------------- bf16 MFMA GEMM ----------------
// 128x128 tile, BK=64, 256 threads (4 waves), 4x4 16x16 acc blocks per wave.
// SEGS=1: K=2048, bf16 out; V-column tiles (bn>=2560) are written TRANSPOSED
// into VT[(b*4+g)*128+d][token].  SEGS=3: hi/lo split fp32 out.
template<int SEGS, bool BF16OUT>
__global__ __launch_bounds__(256)
void gemm_bf16(const unsigned short* __restrict__ A,
               const unsigned short* __restrict__ BT,
               const float* __restrict__ bias,
               void* __restrict__ Cv,
               unsigned short* __restrict__ VTp,
               int N, int AW, int BW) {
  __shared__ unsigned short As[128 * 64];
  __shared__ unsigned short Bs[128 * 64];
  const int tid = threadIdx.x;
  const int w = tid >> 6, l = tid & 63;
  const int bm = blockIdx.y * 128, bn = blockIdx.x * 128;
  const int mbase = (w & 1) * 64, nbase = (w >> 1) * 64;

  f32x4 acc[4][4] = {};

  const int aSeg[3] = {0, 0, 2048};
  const int bSeg[3] = {0, 2048, 0};

  for (int s = 0; s < SEGS; ++s) {
    for (int t = 0; t < 32; ++t) {
      const int ka = aSeg[s] + t * 64;
      const int kb = bSeg[s] + t * 64;
      __syncthreads();
#pragma unroll
      for (int i = 0; i < 4; ++i) {
        int r0 = w * 32 + i * 8;
        int row = r0 + (l >> 3);
        int gr = l & 7;
        const unsigned short* srcA = A + (size_t)(bm + row) * AW + ka + ((gr ^ (row & 7)) << 3);
        GLOAD16(srcA, As + r0 * 64);
        const unsigned short* srcB = BT + (size_t)(bn + row) * BW + kb + ((gr ^ (row & 7)) << 3);
        GLOAD16(srcB, Bs + r0 * 64);
      }
      __syncthreads();
#pragma unroll
      for (int ks = 0; ks < 2; ++ks) {
        bf16x8 af[4], bfr[4];
#pragma unroll
        for (int mb = 0; mb < 4; ++mb) {
          int row = mbase + mb * 16 + (l & 15);
          int g = ks * 4 + (l >> 4);
          af[mb] = *(const bf16x8*)((const char*)As + row * 128 + ((g ^ (row & 7)) << 4));
        }
#pragma unroll
        for (int nb = 0; nb < 4; ++nb) {
          int row = nbase + nb * 16 + (l & 15);
          int g = ks * 4 + (l >> 4);
          bfr[nb] = *(const bf16x8*)((const char*)Bs + row * 128 + ((g ^ (row & 7)) << 4));
        }
#pragma unroll
        for (int mb = 0; mb < 4; ++mb)
#pragma unroll
          for (int nb = 0; nb < 4; ++nb)
            acc[mb][nb] = MFMA16x16x32(af[mb], bfr[nb], acc[mb][nb], 0, 0, 0);
      }
    }
  }

  if (BF16OUT && VTp != nullptr && bn >= 2560) {
    // V tile: write transposed VT[(b*512 + (col-2560))][token]
#pragma unroll
    for (int mb = 0; mb < 4; ++mb) {
      int row0 = bm + mbase + mb * 16 + (l >> 4) * 4;
      int bidx = row0 >> 11, tok = row0 & 2047;
#pragma unroll
      for (int nb = 0; nb < 4; ++nb) {
        int col = bn + nbase + nb * 16 + (l & 15);
        ushort4v o;
#pragma unroll
        for (int r = 0; r < 4; ++r) o[r] = f2bf(acc[mb][nb][r] + bias[col]);
        *(ushort4v*)(VTp + ((size_t)(bidx * 512 + col - 2560)) * 2048 + tok) = o;
      }
    }
    return;
  }
#pragma unroll
  for (int mb = 0; mb < 4; ++mb) {
#pragma unroll
    for (int nb = 0; nb < 4; ++nb) {
#pragma unroll
      for (int r = 0; r < 4; ++r) {
        int row = bm + mbase + mb * 16 + (l >> 4) * 4 + r;
        int col = bn + nbase + nb * 16 + (l & 15);
        float v = acc[mb][nb][r] + bias[col];
        if (BF16OUT) ((unsigned short*)Cv)[(size_t)row * N + col] = f2bf(v);
        else         ((float*)Cv)[(size_t)row * N + col] = v;
      }
    }
  }
}

// ---------------- MFMA flash attention ----------------
// grid (SS/128, B*16). 4 waves; wave w owns q-rows [w*32, w*32+32) (2 m-blocks).
// K tile 64x128 and V^T tile 128x64 staged via gload_lds (pre-swizzled source).
// P per-wave 32x64 bf16 via LDS. Online softmax fp32.
__global__ __launch_bounds__(256, 2)
void attn_mfma(const unsigned short* __restrict__ QKV,
               const unsigned short* __restrict__ VT,
               unsigned short* __restrict__ AOp) {
  __shared__ unsigned short Ks[64 * 128];    // [key][d]     16KB
  __shared__ unsigned short VsT[128 * 64];   // [d][key]     16KB
  __shared__ unsigned short Ps[4 * 32 * 64]; // per-wave P   16KB
  const int tid = threadIdx.x;
  const int w = tid >> 6, l = tid & 63;
  const int qt = blockIdx.x;
  const int bh = blockIdx.y;
  const int b = bh >> 4, h = bh & 15, g = h >> 2;
  const float scale = 0.08838834764831845f;  // 1/sqrt(128)

  bf16x8 qf[2][4];
#pragma unroll
  for (int mb = 0; mb < 2; ++mb) {
    const int qrow = b * SS + qt * 128 + w * 32 + mb * 16 + (l & 15);
    const unsigned short* qp = QKV + (size_t)qrow * NQKV + h * 128 + ((l >> 4) << 3);
#pragma unroll
    for (int ks = 0; ks < 4; ++ks) qf[mb][ks] = *(const bf16x8*)(qp + ks * 32);
  }

  f32x4 oacc[2][8] = {};
  float mrow[2][4], lrow[2][4];
#pragma unroll
  for (int mb = 0; mb < 2; ++mb)
#pragma unroll
    for (int r = 0; r < 4; ++r) { mrow[mb][r] = -1e30f; lrow[mb][r] = 0.f; }

  const unsigned short* kbase = QKV + (size_t)b * SS * NQKV + 2048 + g * 128;
  const unsigned short* vtbase = VT + (size_t)(b * 4 + g) * 128 * 2048;

  for (int kt = 0; kt < SS / 64; ++kt) {
    __syncthreads();
    // stage K tile rows w*16..w*16+15 (row = key, 256B/row, 16 lanes/row)
#pragma unroll
    for (int i = 0; i < 4; ++i) {
      int r0 = w * 16 + i * 4;
      int row = r0 + (l >> 4);
      int gr = l & 15;
      const unsigned short* src = kbase + (size_t)(kt * 64 + row) * NQKV
                                  + ((gr ^ (row & 7)) << 3);
      GLOAD16(src, Ks + r0 * 128);
    }
    // stage V^T tile rows w*32..w*32+31 (row = d, 128B/row, 8 lanes/row)
#pragma unroll
    for (int i = 0; i < 4; ++i) {
      int r0 = w * 32 + i * 8;
      int row = r0 + (l >> 3);
      int gr = l & 7;
      const unsigned short* src = vtbase + (size_t)row * 2048 + kt * 64
                                  + ((gr ^ (row & 7)) << 3);
      GLOAD16(src, VsT + r0 * 64);
    }
    __syncthreads();

    // QK^T: sacc[mb][nb] = Q(16x128) @ K^T
    f32x4 sacc[2][4] = {};
#pragma unroll
    for (int ks = 0; ks < 4; ++ks) {
#pragma unroll
      for (int nb = 0; nb < 4; ++nb) {
        int key = nb * 16 + (l & 15);
        int grn = ks * 4 + (l >> 4);
        bf16x8 kf = *(const bf16x8*)((const char*)Ks + key * 256 + ((grn ^ (key & 7)) << 4));
#pragma unroll
        for (int mb = 0; mb < 2; ++mb)
          sacc[mb][nb] = MFMA16x16x32(qf[mb][ks], kf, sacc[mb][nb], 0, 0, 0);
      }
    }

    // online softmax; P -> LDS (bf16)
    float alpha[2][4];
    char* pw = (char*)Ps + w * 4096;
#pragma unroll
    for (int mb = 0; mb < 2; ++mb) {
#pragma unroll
      for (int r = 0; r < 4; ++r) {
        float s0 = sacc[mb][0][r] * scale, s1 = sacc[mb][1][r] * scale,
              s2 = sacc[mb][2][r] * scale, s3 = sacc[mb][3][r] * scale;
        float mx = fmaxf(fmaxf(s0, s1), fmaxf(s2, s3));
#pragma unroll
        for (int msk = 1; msk < 16; msk <<= 1) mx = fmaxf(mx, __shfl_xor(mx, msk, 64));
        float mnew = fmaxf(mrow[mb][r], mx);
        alpha[mb][r] = __expf(mrow[mb][r] - mnew);
        float e0 = __expf(s0 - mnew), e1 = __expf(s1 - mnew),
              e2 = __expf(s2 - mnew), e3 = __expf(s3 - mnew);
        float sum = e0 + e1 + e2 + e3;
#pragma unroll
        for (int msk = 1; msk < 16; msk <<= 1) sum += __shfl_xor(sum, msk, 64);
        lrow[mb][r] = lrow[mb][r] * alpha[mb][r] + sum;
        mrow[mb][r] = mnew;
        int prow = mb * 16 + (l >> 4) * 4 + r;
        int base = prow * 128 + (l & 15) * 2;
        int swz = (prow & 7) << 4;
        *(unsigned short*)(pw + ((base +  0) ^ swz)) = f2bf(e0);
        *(unsigned short*)(pw + ((base + 32) ^ swz)) = f2bf(e1);
        *(unsigned short*)(pw + ((base + 64) ^ swz)) = f2bf(e2);
        *(unsigned short*)(pw + ((base + 96) ^ swz)) = f2bf(e3);
      }
    }

    // rescale O accumulators
#pragma unroll
    for (int mb = 0; mb < 2; ++mb)
#pragma unroll
      for (int nb = 0; nb < 8; ++nb)
#pragma unroll
        for (int r = 0; r < 4; ++r) oacc[mb][nb][r] *= alpha[mb][r];

    // PV: O(32x128) += P(32x64) @ V(64x128)
#pragma unroll
    for (int ks = 0; ks < 2; ++ks) {
      int grn = ks * 4 + (l >> 4);
      bf16x8 pf[2];
#pragma unroll
      for (int mb = 0; mb < 2; ++mb) {
        int prow = mb * 16 + (l & 15);
        pf[mb] = *(const bf16x8*)(pw + prow * 128 + ((grn ^ (prow & 7)) << 4));
      }
#pragma unroll
      for (int nb = 0; nb < 8; ++nb) {
        int d = nb * 16 + (l & 15);
        bf16x8 vf = *(const bf16x8*)((const char*)VsT + d * 128 + ((grn ^ (d & 7)) << 4));
#pragma unroll
        for (int mb = 0; mb < 2; ++mb)
          oacc[mb][nb] = MFMA16x16x32(pf[mb], vf, oacc[mb][nb], 0, 0, 0);
      }
    }
  }

  // epilogue: AO = [hi(2048) | lo(2048)] bf16
#pragma unroll
  for (int mb = 0; mb < 2; ++mb) {
    const int rowb = b * SS + qt * 128 + w * 32 + mb * 16 + (l >> 4) * 4;
#pragma unroll
    for (int r = 0; r < 4; ++r) {
      float rl = 1.0f / lrow[mb][r];
      unsigned short* outp = AOp + (size_t)(rowb + r) * AO_W + h * 128 + (l & 15);
#pragma unroll
      for (int nb = 0; nb < 8; ++nb) {
        float v = oacc[mb][nb][r] * rl;
        unsigned short hi = f2bf(v);
        unsigned short lo = f2bf(v - bf2f(hi));
        outp[nb * 16] = hi;
        outp[nb * 16 + 2048] = lo;
      }
    }
  }
}

extern "C" void kernel_launch(void* const* d_in, const int* in_sizes, int n_in,
                              void* d_out, int out_size, void* d_ws, size_t ws_size,
                              hipStream_t stream) {
  const float* x  = (const float*)d_in[0];
  const float* Wq = (const float*)d_in[1];
  const float* bq = (const float*)d_in[2];
  const float* Wk = (const float*)d_in[3];
  const float* bk = (const float*)d_in[4];
  const float* Wv = (const float*)d_in[5];
  const float* bv = (const float*)d_in[6];
  const float* Wo = (const float*)d_in[7];
  const float* bo = (const float*)d_in[8];
  float* out = (float*)d_out;

  char* ws = (char*)d_ws;
  unsigned short* x_bf  = (unsigned short*)(ws);              // 16.8 MB
  unsigned short* WqkvT = (unsigned short*)(ws + 16777216);   // 12.6 MB
  unsigned short* AO    = (unsigned short*)(ws);              // 33.6 MB (reuses x_bf/WqkvT)
  float*          bqkv  = (float*)(ws + 35651584);
  unsigned short* WoT   = (unsigned short*)(ws + 36700160);   // 16.8 MB
  unsigned short* QKV   = (unsigned short*)(ws + 54525952);   // 25.2 MB
  unsigned short* VT    = (unsigned short*)(ws + 79691776);   // 4.2 MB (ends 83886080)

  conv_x<<<4096, 256, 0, stream>>>(x, x_bf);
  pack_wqkvT<<<dim3(64, 96), 256, 0, stream>>>(Wq, Wk, Wv, WqkvT);
  pack_bias<<<12, 256, 0, stream>>>(bq, bk, bv, bqkv);
  pack_woT<<<dim3(64, 64), 256, 0, stream>>>(Wo, WoT);
  gemm_bf16<1, true><<<dim3(24, 32), 256, 0, stream>>>(x_bf, WqkvT, bqkv, QKV, VT,
                                                        NQKV, 2048, 2048);
  attn_mfma<<<dim3(16, 32), 256, 0, stream>>>(QKV, VT, AO);
  gemm_bf16<3, false><<<dim3(16, 32), 256, 0, stream>>>(AO, WoT, bo, out, nullptr,
                                                         2048, 4096, 4096);
}

// Round 4
// 296.369 us; speedup vs baseline: 9.2107x; 1.1945x over previous
//
#include <hip/hip_runtime.h>
#include <math.h>
#include <stdint.h>

#define D_MODEL 2048
#define SS 2048
#define BB 2
#define ROWS (BB*SS)      // 4096
#define NQKV 3072
#define AO_W 4096

typedef __attribute__((ext_vector_type(8))) short bf16x8;
typedef __attribute__((ext_vector_type(4))) float f32x4;
typedef __attribute__((ext_vector_type(8))) unsigned short ushort8v;
typedef __attribute__((ext_vector_type(4))) unsigned short ushort4v;

// scale(1/sqrt(128)) * log2(e): folded into Wk/bk so QK^T scores are exp2-domain
#define KSCALE 0.12751879566649053f

__device__ __forceinline__ unsigned short f2bf(float f) {
  uint32_t u = __builtin_bit_cast(uint32_t, f);
  return (unsigned short)((u + 0x7FFFu + ((u >> 16) & 1u)) >> 16);
}
__device__ __forceinline__ float bf2f(unsigned short h) {
  uint32_t u = ((uint32_t)h) << 16;
  return __builtin_bit_cast(float, u);
}

#define MFMA16x16x32 __builtin_amdgcn_mfma_f32_16x16x32_bf16

#define GLOAD16(gsrc, ldst) \
  __builtin_amdgcn_global_load_lds((const __attribute__((address_space(1))) void*)(gsrc), \
      (__attribute__((address_space(3))) void*)(ldst), 16, 0, 0)

// ---------------- fp32 -> bf16 convert (x) ----------------
__global__ __launch_bounds__(256)
void conv_x(const float* __restrict__ x, unsigned short* __restrict__ xb) {
  size_t i = ((size_t)blockIdx.x * 256 + threadIdx.x) * 8;
  float4 v0 = *(const float4*)(x + i);
  float4 v1 = *(const float4*)(x + i + 4);
  ushort8v o;
  o[0]=f2bf(v0.x); o[1]=f2bf(v0.y); o[2]=f2bf(v0.z); o[3]=f2bf(v0.w);
  o[4]=f2bf(v1.x); o[5]=f2bf(v1.y); o[6]=f2bf(v1.z); o[7]=f2bf(v1.w);
  *(ushort8v*)(xb + i) = o;
}

// ---------------- pack Wq|Wk|Wv transposed -> WT[3072][2048] bf16 ----------------
// K block (cols 2048..2560) is pre-scaled by KSCALE (softmax scale * log2e).
__global__ __launch_bounds__(256)
void pack_wqkvT(const float* __restrict__ Wq, const float* __restrict__ Wk,
                const float* __restrict__ Wv, unsigned short* __restrict__ WT) {
  __shared__ float T[32][33];
  const int k0 = blockIdx.x * 32, n0 = blockIdx.y * 32;
  const int tid = threadIdx.x;
  const float* W; int nbase, stride; float fac = 1.0f;
  if (n0 < 2048)      { W = Wq; nbase = n0;        stride = 2048; }
  else if (n0 < 2560) { W = Wk; nbase = n0 - 2048; stride = 512; fac = KSCALE; }
  else                { W = Wv; nbase = n0 - 2560; stride = 512;  }
  int r = tid >> 3, c = (tid & 7) * 4;
  float4 v = *(const float4*)(W + (size_t)(k0 + r) * stride + nbase + c);
  T[c + 0][r] = v.x; T[c + 1][r] = v.y; T[c + 2][r] = v.z; T[c + 3][r] = v.w;
  __syncthreads();
  ushort4v o;
  o[0]=f2bf(T[r][c]*fac); o[1]=f2bf(T[r][c+1]*fac);
  o[2]=f2bf(T[r][c+2]*fac); o[3]=f2bf(T[r][c+3]*fac);
  *(ushort4v*)(WT + (size_t)(n0 + r) * 2048 + k0 + c) = o;
}

// ---------------- pack Wo transposed hi|lo -> WoT[2048][4096] bf16 ----------------
__global__ __launch_bounds__(256)
void pack_woT(const float* __restrict__ Wo, unsigned short* __restrict__ WoT) {
  __shared__ float T[32][33];
  const int k0 = blockIdx.x * 32, n0 = blockIdx.y * 32;
  const int tid = threadIdx.x;
  int r = tid >> 3, c = (tid & 7) * 4;
  float4 v = *(const float4*)(Wo + (size_t)(k0 + r) * 2048 + n0 + c);
  T[c+0][r]=v.x; T[c+1][r]=v.y; T[c+2][r]=v.z; T[c+3][r]=v.w;
  __syncthreads();
  ushort4v oh, ol;
#pragma unroll
  for (int j = 0; j < 4; ++j) {
    float f = T[r][c + j];
    unsigned short hb = f2bf(f);
    oh[j] = hb;
    ol[j] = f2bf(f - bf2f(hb));
  }
  *(ushort4v*)(WoT + (size_t)(n0 + r) * 4096 + k0 + c) = oh;
  *(ushort4v*)(WoT + (size_t)(n0 + r) * 4096 + 2048 + k0 + c) = ol;
}

__global__ void pack_bias(const float* __restrict__ bq, const float* __restrict__ bk,
                          const float* __restrict__ bv, float* __restrict__ bqkv) {
  int i = blockIdx.x * 256 + threadIdx.x;
  if (i >= 3072) return;
  bqkv[i] = i < 2048 ? bq[i]
          : (i < 2560 ? bk[i - 2048] * KSCALE : bv[i - 2560]);
}

// ---------------- bf16 MFMA GEMM ----------------
template<int SEGS, bool BF16OUT>
__global__ __launch_bounds__(256)
void gemm_bf16(const unsigned short* __restrict__ A,
               const unsigned short* __restrict__ BT,
               const float* __restrict__ bias,
               void* __restrict__ Cv,
               unsigned short* __restrict__ VTp,
               int N, int AW, int BW) {
  __shared__ unsigned short As[128 * 64];
  __shared__ unsigned short Bs[128 * 64];
  const int tid = threadIdx.x;
  const int w = tid >> 6, l = tid & 63;
  const int bm = blockIdx.y * 128, bn = blockIdx.x * 128;
  const int mbase = (w & 1) * 64, nbase = (w >> 1) * 64;

  f32x4 acc[4][4] = {};

  const int aSeg[3] = {0, 0, 2048};
  const int bSeg[3] = {0, 2048, 0};

  for (int s = 0; s < SEGS; ++s) {
    for (int t = 0; t < 32; ++t) {
      const int ka = aSeg[s] + t * 64;
      const int kb = bSeg[s] + t * 64;
      __syncthreads();
#pragma unroll
      for (int i = 0; i < 4; ++i) {
        int r0 = w * 32 + i * 8;
        int row = r0 + (l >> 3);
        int gr = l & 7;
        const unsigned short* srcA = A + (size_t)(bm + row) * AW + ka + ((gr ^ (row & 7)) << 3);
        GLOAD16(srcA, As + r0 * 64);
        const unsigned short* srcB = BT + (size_t)(bn + row) * BW + kb + ((gr ^ (row & 7)) << 3);
        GLOAD16(srcB, Bs + r0 * 64);
      }
      __syncthreads();
#pragma unroll
      for (int ks = 0; ks < 2; ++ks) {
        bf16x8 af[4], bfr[4];
#pragma unroll
        for (int mb = 0; mb < 4; ++mb) {
          int row = mbase + mb * 16 + (l & 15);
          int g = ks * 4 + (l >> 4);
          af[mb] = *(const bf16x8*)((const char*)As + row * 128 + ((g ^ (row & 7)) << 4));
        }
#pragma unroll
        for (int nb = 0; nb < 4; ++nb) {
          int row = nbase + nb * 16 + (l & 15);
          int g = ks * 4 + (l >> 4);
          bfr[nb] = *(const bf16x8*)((const char*)Bs + row * 128 + ((g ^ (row & 7)) << 4));
        }
#pragma unroll
        for (int mb = 0; mb < 4; ++mb)
#pragma unroll
          for (int nb = 0; nb < 4; ++nb)
            acc[mb][nb] = MFMA16x16x32(af[mb], bfr[nb], acc[mb][nb], 0, 0, 0);
      }
    }
  }

  if (BF16OUT && VTp != nullptr && bn >= 2560) {
#pragma unroll
    for (int mb = 0; mb < 4; ++mb) {
      int row0 = bm + mbase + mb * 16 + (l >> 4) * 4;
      int bidx = row0 >> 11, tok = row0 & 2047;
#pragma unroll
      for (int nb = 0; nb < 4; ++nb) {
        int col = bn + nbase + nb * 16 + (l & 15);
        ushort4v o;
#pragma unroll
        for (int r = 0; r < 4; ++r) o[r] = f2bf(acc[mb][nb][r] + bias[col]);
        *(ushort4v*)(VTp + ((size_t)(bidx * 512 + col - 2560)) * 2048 + tok) = o;
      }
    }
    return;
  }
#pragma unroll
  for (int mb = 0; mb < 4; ++mb) {
#pragma unroll
    for (int nb = 0; nb < 4; ++nb) {
#pragma unroll
      for (int r = 0; r < 4; ++r) {
        int row = bm + mbase + mb * 16 + (l >> 4) * 4 + r;
        int col = bn + nbase + nb * 16 + (l & 15);
        float v = acc[mb][nb][r] + bias[col];
        if (BF16OUT) ((unsigned short*)Cv)[(size_t)row * N + col] = f2bf(v);
        else         ((float*)Cv)[(size_t)row * N + col] = v;
      }
    }
  }
}

// ---------------- MFMA flash attention (swapped-QK^T softmax) ----------------
// grid (SS/128, B*16). 4 waves; wave w owns q-rows [w*32, w*32+32) (2 m-blocks).
// Scores computed as S^T = mfma(K,Q): lane owns q-row (l&15), 16 in-lane keys.
// Softmax in exp2-domain (scale*log2e folded into Wk). Defer-max THR=8.
__global__ __launch_bounds__(256, 2)
void attn_mfma(const unsigned short* __restrict__ QKV,
               const unsigned short* __restrict__ VT,
               unsigned short* __restrict__ AOp) {
  __shared__ unsigned short Ks[64 * 128];    // [key][d]     16KB
  __shared__ unsigned short VsT[128 * 64];   // [d][key]     16KB
  __shared__ unsigned short Ps[4 * 32 * 64]; // per-wave P   16KB
  const int tid = threadIdx.x;
  const int w = tid >> 6, l = tid & 63;
  const int qt = blockIdx.x;
  const int bh = blockIdx.y;
  const int b = bh >> 4, h = bh & 15, g = h >> 2;
  const int lg = l >> 4;         // lane group 0..3
  const int lr16 = l & 15;       // lane row within 16

  bf16x8 qf[2][4];
#pragma unroll
  for (int mb = 0; mb < 2; ++mb) {
    const int qrow = b * SS + qt * 128 + w * 32 + mb * 16 + lr16;
    const unsigned short* qp = QKV + (size_t)qrow * NQKV + h * 128 + (lg << 3);
#pragma unroll
    for (int ks = 0; ks < 4; ++ks) qf[mb][ks] = *(const bf16x8*)(qp + ks * 32);
  }

  f32x4 oacc[2][8] = {};
  float mrow[2] = {-1e30f, -1e30f};   // running max (exp2 domain), row = l&15
  float lrow[2] = {0.f, 0.f};

  const unsigned short* kbase = QKV + (size_t)b * SS * NQKV + 2048 + g * 128;
  const unsigned short* vtbase = VT + (size_t)(b * 4 + g) * 128 * 2048;
  char* pw = (char*)Ps + w * 4096;

  for (int kt = 0; kt < SS / 64; ++kt) {
    __syncthreads();
    // stage K tile rows w*16..w*16+15
#pragma unroll
    for (int i = 0; i < 4; ++i) {
      int r0 = w * 16 + i * 4;
      int row = r0 + (l >> 4);
      int gr = l & 15;
      const unsigned short* src = kbase + (size_t)(kt * 64 + row) * NQKV
                                  + ((gr ^ (row & 7)) << 3);
      GLOAD16(src, Ks + r0 * 128);
    }
    // stage V^T tile rows w*32..w*32+31
#pragma unroll
    for (int i = 0; i < 4; ++i) {
      int r0 = w * 32 + i * 8;
      int row = r0 + (l >> 3);
      int gr = l & 7;
      const unsigned short* src = vtbase + (size_t)row * 2048 + kt * 64
                                  + ((gr ^ (row & 7)) << 3);
      GLOAD16(src, VsT + r0 * 64);
    }
    __syncthreads();

    // QK^T (swapped): sacc[mb][nb] = S^T fragment:
    //   score[key = 16nb+4*lg+r][qrow = mb*16+lr16]
    f32x4 sacc[2][4] = {};
#pragma unroll
    for (int ks = 0; ks < 4; ++ks) {
#pragma unroll
      for (int nb = 0; nb < 4; ++nb) {
        int key = nb * 16 + lr16;
        int grn = ks * 4 + lg;
        bf16x8 kf = *(const bf16x8*)((const char*)Ks + key * 256 + ((grn ^ (key & 7)) << 4));
#pragma unroll
        for (int mb = 0; mb < 2; ++mb)
          sacc[mb][nb] = MFMA16x16x32(kf, qf[mb][ks], sacc[mb][nb], 0, 0, 0);
      }
    }

    // softmax (exp2 domain), defer-max, P^T quads -> LDS
    const int rowswz = (l & 7) << 4;
#pragma unroll
    for (int mb = 0; mb < 2; ++mb) {
      float nbm[4];
#pragma unroll
      for (int nb = 0; nb < 4; ++nb)
        nbm[nb] = fmaxf(fmaxf(sacc[mb][nb][0], sacc[mb][nb][1]),
                        fmaxf(sacc[mb][nb][2], sacc[mb][nb][3]));
      float pmax = fmaxf(fmaxf(nbm[0], nbm[1]), fmaxf(nbm[2], nbm[3]));
      pmax = fmaxf(pmax, __shfl_xor(pmax, 16, 64));
      pmax = fmaxf(pmax, __shfl_xor(pmax, 32, 64));
      if (__any(pmax > mrow[mb] + 11.5416f)) {   // 8 * log2e
        float mnew = fmaxf(mrow[mb], pmax);
        float alpha = __builtin_amdgcn_exp2f(mrow[mb] - mnew);
        lrow[mb] *= alpha;
        mrow[mb] = mnew;
        float av[4];
#pragma unroll
        for (int r = 0; r < 4; ++r) av[r] = __shfl(alpha, lg * 4 + r, 64);
#pragma unroll
        for (int db = 0; db < 8; ++db) {
          oacc[mb][db][0] *= av[0]; oacc[mb][db][1] *= av[1];
          oacc[mb][db][2] *= av[2]; oacc[mb][db][3] *= av[3];
        }
      }
      float ssum = 0.f;
      char* pwm = pw + (mb * 16 + lr16) * 128;
#pragma unroll
      for (int nb = 0; nb < 4; ++nb) {
        float e0 = __builtin_amdgcn_exp2f(sacc[mb][nb][0] - mrow[mb]);
        float e1 = __builtin_amdgcn_exp2f(sacc[mb][nb][1] - mrow[mb]);
        float e2 = __builtin_amdgcn_exp2f(sacc[mb][nb][2] - mrow[mb]);
        float e3 = __builtin_amdgcn_exp2f(sacc[mb][nb][3] - mrow[mb]);
        ssum += (e0 + e1) + (e2 + e3);
        uint32_t p01, p23;
        asm("v_cvt_pk_bf16_f32 %0, %1, %2" : "=v"(p01) : "v"(e0), "v"(e1));
        asm("v_cvt_pk_bf16_f32 %0, %1, %2" : "=v"(p23) : "v"(e2), "v"(e3));
        uint2 q; q.x = p01; q.y = p23;
        *(uint2*)(pwm + ((((nb << 2) + lg) << 3) ^ rowswz)) = q;
      }
      ssum += __shfl_xor(ssum, 16, 64);
      ssum += __shfl_xor(ssum, 32, 64);
      lrow[mb] += ssum;
    }

    // PV: O(32x128) += P(32x64) @ V(64x128)
#pragma unroll
    for (int ks = 0; ks < 2; ++ks) {
      int grn = ks * 4 + lg;
      bf16x8 pf[2];
#pragma unroll
      for (int mb = 0; mb < 2; ++mb) {
        int prow = mb * 16 + lr16;
        pf[mb] = *(const bf16x8*)(pw + prow * 128 + ((grn ^ (prow & 7)) << 4));
      }
#pragma unroll
      for (int nb = 0; nb < 8; ++nb) {
        int d = nb * 16 + lr16;
        bf16x8 vf = *(const bf16x8*)((const char*)VsT + d * 128 + ((grn ^ (d & 7)) << 4));
#pragma unroll
        for (int mb = 0; mb < 2; ++mb)
          oacc[mb][nb] = MFMA16x16x32(pf[mb], vf, oacc[mb][nb], 0, 0, 0);
      }
    }
  }

  // epilogue: AO = [hi(2048) | lo(2048)] bf16
#pragma unroll
  for (int mb = 0; mb < 2; ++mb) {
    const int rowb = b * SS + qt * 128 + w * 32 + mb * 16 + lg * 4;
#pragma unroll
    for (int r = 0; r < 4; ++r) {
      float rl = 1.0f / __shfl(lrow[mb], lg * 4 + r, 64);
      unsigned short* outp = AOp + (size_t)(rowb + r) * AO_W + h * 128 + lr16;
#pragma unroll
      for (int nb = 0; nb < 8; ++nb) {
        float v = oacc[mb][nb][r] * rl;
        unsigned short hi = f2bf(v);
        unsigned short lo = f2bf(v - bf2f(hi));
        outp[nb * 16] = hi;
        outp[nb * 16 + 2048] = lo;
      }
    }
  }
}

extern "C" void kernel_launch(void* const* d_in, const int* in_sizes, int n_in,
                              void* d_out, int out_size, void* d_ws, size_t ws_size,
                              hipStream_t stream) {
  const float* x  = (const float*)d_in[0];
  const float* Wq = (const float*)d_in[1];
  const float* bq = (const float*)d_in[2];
  const float* Wk = (const float*)d_in[3];
  const float* bk = (const float*)d_in[4];
  const float* Wv = (const float*)d_in[5];
  const float* bv = (const float*)d_in[6];
  const float* Wo = (const float*)d_in[7];
  const float* bo = (const float*)d_in[8];
  float* out = (float*)d_out;

  char* ws = (char*)d_ws;
  unsigned short* x_bf  = (unsigned short*)(ws);              // 16.8 MB
  unsigned short* WqkvT = (unsigned short*)(ws + 16777216);   // 12.6 MB
  unsigned short* AO    = (unsigned short*)(ws);              // 33.6 MB (reuses x_bf/WqkvT)
  float*          bqkv  = (float*)(ws + 35651584);
  unsigned short* WoT   = (unsigned short*)(ws + 36700160);   // 16.8 MB
  unsigned short* QKV   = (unsigned short*)(ws + 54525952);   // 25.2 MB
  unsigned short* VT    = (unsigned short*)(ws + 79691776);   // 4.2 MB

  conv_x<<<4096, 256, 0, stream>>>(x, x_bf);
  pack_wqkvT<<<dim3(64, 96), 256, 0, stream>>>(Wq, Wk, Wv, WqkvT);
  pack_bias<<<12, 256, 0, stream>>>(bq, bk, bv, bqkv);
  pack_woT<<<dim3(64, 64), 256, 0, stream>>>(Wo, WoT);
  gemm_bf16<1, true><<<dim3(24, 32), 256, 0, stream>>>(x_bf, WqkvT, bqkv, QKV, VT,
                                                        NQKV, 2048, 2048);
  attn_mfma<<<dim3(16, 32), 256, 0, stream>>>(QKV, VT, AO);
  gemm_bf16<3, false><<<dim3(16, 32), 256, 0, stream>>>(AO, WoT, bo, out, nullptr,
                                                         2048, 4096, 4096);
}

// Round 5
// 252.155 us; speedup vs baseline: 10.8257x; 1.1753x over previous
//
#include <hip/hip_runtime.h>
#include <math.h>
#include <stdint.h>

#define D_MODEL 2048
#define SS 2048
#define BB 2
#define ROWS (BB*SS)      // 4096
#define NQKV 3072

typedef __attribute__((ext_vector_type(8))) short bf16x8;
typedef __attribute__((ext_vector_type(4))) float f32x4;
typedef __attribute__((ext_vector_type(8))) unsigned short ushort8v;
typedef __attribute__((ext_vector_type(4))) unsigned short ushort4v;

// scale(1/sqrt(128)) * log2(e): folded into Wk/bk so QK^T scores are exp2-domain
#define KSCALE 0.12751879566649053f

__device__ __forceinline__ unsigned short f2bf(float f) {
  uint32_t u = __builtin_bit_cast(uint32_t, f);
  return (unsigned short)((u + 0x7FFFu + ((u >> 16) & 1u)) >> 16);
}
__device__ __forceinline__ float bf2f(unsigned short h) {
  uint32_t u = ((uint32_t)h) << 16;
  return __builtin_bit_cast(float, u);
}

#define MFMA16x16x32 __builtin_amdgcn_mfma_f32_16x16x32_bf16

#define GLOAD16(gsrc, ldst) \
  __builtin_amdgcn_global_load_lds((const __attribute__((address_space(1))) void*)(gsrc), \
      (__attribute__((address_space(3))) void*)(ldst), 16, 0, 0)

// ---------------- fp32 -> bf16 convert (x) ----------------
__global__ __launch_bounds__(256)
void conv_x(const float* __restrict__ x, unsigned short* __restrict__ xb) {
  size_t i = ((size_t)blockIdx.x * 256 + threadIdx.x) * 8;
  float4 v0 = *(const float4*)(x + i);
  float4 v1 = *(const float4*)(x + i + 4);
  ushort8v o;
  o[0]=f2bf(v0.x); o[1]=f2bf(v0.y); o[2]=f2bf(v0.z); o[3]=f2bf(v0.w);
  o[4]=f2bf(v1.x); o[5]=f2bf(v1.y); o[6]=f2bf(v1.z); o[7]=f2bf(v1.w);
  *(ushort8v*)(xb + i) = o;
}

// ---------------- pack Wq|Wk|Wv transposed -> WT[3072][2048] bf16 ----------------
// K block (cols 2048..2560) is pre-scaled by KSCALE (softmax scale * log2e).
__global__ __launch_bounds__(256)
void pack_wqkvT(const float* __restrict__ Wq, const float* __restrict__ Wk,
                const float* __restrict__ Wv, unsigned short* __restrict__ WT) {
  __shared__ float T[32][33];
  const int k0 = blockIdx.x * 32, n0 = blockIdx.y * 32;
  const int tid = threadIdx.x;
  const float* W; int nbase, stride; float fac = 1.0f;
  if (n0 < 2048)      { W = Wq; nbase = n0;        stride = 2048; }
  else if (n0 < 2560) { W = Wk; nbase = n0 - 2048; stride = 512; fac = KSCALE; }
  else                { W = Wv; nbase = n0 - 2560; stride = 512;  }
  int r = tid >> 3, c = (tid & 7) * 4;
  float4 v = *(const float4*)(W + (size_t)(k0 + r) * stride + nbase + c);
  T[c + 0][r] = v.x; T[c + 1][r] = v.y; T[c + 2][r] = v.z; T[c + 3][r] = v.w;
  __syncthreads();
  ushort4v o;
  o[0]=f2bf(T[r][c]*fac); o[1]=f2bf(T[r][c+1]*fac);
  o[2]=f2bf(T[r][c+2]*fac); o[3]=f2bf(T[r][c+3]*fac);
  *(ushort4v*)(WT + (size_t)(n0 + r) * 2048 + k0 + c) = o;
}

// ---------------- pack Wo transposed hi|lo -> WoT[2048][4096] bf16 ----------------
__global__ __launch_bounds__(256)
void pack_woT(const float* __restrict__ Wo, unsigned short* __restrict__ WoT) {
  __shared__ float T[32][33];
  const int k0 = blockIdx.x * 32, n0 = blockIdx.y * 32;
  const int tid = threadIdx.x;
  int r = tid >> 3, c = (tid & 7) * 4;
  float4 v = *(const float4*)(Wo + (size_t)(k0 + r) * 2048 + n0 + c);
  T[c+0][r]=v.x; T[c+1][r]=v.y; T[c+2][r]=v.z; T[c+3][r]=v.w;
  __syncthreads();
  ushort4v oh, ol;
#pragma unroll
  for (int j = 0; j < 4; ++j) {
    float f = T[r][c + j];
    unsigned short hb = f2bf(f);
    oh[j] = hb;
    ol[j] = f2bf(f - bf2f(hb));
  }
  *(ushort4v*)(WoT + (size_t)(n0 + r) * 4096 + k0 + c) = oh;
  *(ushort4v*)(WoT + (size_t)(n0 + r) * 4096 + 2048 + k0 + c) = ol;
}

__global__ void pack_bias(const float* __restrict__ bq, const float* __restrict__ bk,
                          const float* __restrict__ bv, float* __restrict__ bqkv) {
  int i = blockIdx.x * 256 + threadIdx.x;
  if (i >= 3072) return;
  bqkv[i] = i < 2048 ? bq[i]
          : (i < 2560 ? bk[i - 2048] * KSCALE : bv[i - 2560]);
}

// ---------------- bf16 MFMA GEMM (QKV projection) ----------------
__global__ __launch_bounds__(256)
void gemm_qkv(const unsigned short* __restrict__ A,
              const unsigned short* __restrict__ BT,
              const float* __restrict__ bias,
              unsigned short* __restrict__ Cv,
              unsigned short* __restrict__ VTp) {
  __shared__ unsigned short As[128 * 64];
  __shared__ unsigned short Bs[128 * 64];
  const int tid = threadIdx.x;
  const int w = tid >> 6, l = tid & 63;
  const int bm = blockIdx.y * 128, bn = blockIdx.x * 128;
  const int mbase = (w & 1) * 64, nbase = (w >> 1) * 64;

  f32x4 acc[4][4] = {};

  for (int t = 0; t < 32; ++t) {
    const int k = t * 64;
    __syncthreads();
#pragma unroll
    for (int i = 0; i < 4; ++i) {
      int r0 = w * 32 + i * 8;
      int row = r0 + (l >> 3);
      int gr = l & 7;
      GLOAD16(A + (size_t)(bm + row) * 2048 + k + ((gr ^ (row & 7)) << 3), As + r0 * 64);
      GLOAD16(BT + (size_t)(bn + row) * 2048 + k + ((gr ^ (row & 7)) << 3), Bs + r0 * 64);
    }
    __syncthreads();
#pragma unroll
    for (int ks = 0; ks < 2; ++ks) {
      bf16x8 af[4], bfr[4];
#pragma unroll
      for (int mb = 0; mb < 4; ++mb) {
        int row = mbase + mb * 16 + (l & 15);
        int g = ks * 4 + (l >> 4);
        af[mb] = *(const bf16x8*)((const char*)As + row * 128 + ((g ^ (row & 7)) << 4));
      }
#pragma unroll
      for (int nb = 0; nb < 4; ++nb) {
        int row = nbase + nb * 16 + (l & 15);
        int g = ks * 4 + (l >> 4);
        bfr[nb] = *(const bf16x8*)((const char*)Bs + row * 128 + ((g ^ (row & 7)) << 4));
      }
#pragma unroll
      for (int mb = 0; mb < 4; ++mb)
#pragma unroll
        for (int nb = 0; nb < 4; ++nb)
          acc[mb][nb] = MFMA16x16x32(af[mb], bfr[nb], acc[mb][nb], 0, 0, 0);
    }
  }

  if (bn >= 2560) {
    // V tile: write transposed VT[(b*512 + (col-2560))][token]
#pragma unroll
    for (int mb = 0; mb < 4; ++mb) {
      int row0 = bm + mbase + mb * 16 + (l >> 4) * 4;
      int bidx = row0 >> 11, tok = row0 & 2047;
#pragma unroll
      for (int nb = 0; nb < 4; ++nb) {
        int col = bn + nbase + nb * 16 + (l & 15);
        ushort4v o;
#pragma unroll
        for (int r = 0; r < 4; ++r) o[r] = f2bf(acc[mb][nb][r] + bias[col]);
        *(ushort4v*)(VTp + ((size_t)(bidx * 512 + col - 2560)) * 2048 + tok) = o;
      }
    }
    return;
  }
#pragma unroll
  for (int mb = 0; mb < 4; ++mb) {
#pragma unroll
    for (int nb = 0; nb < 4; ++nb) {
#pragma unroll
      for (int r = 0; r < 4; ++r) {
        int row = bm + mbase + mb * 16 + (l >> 4) * 4 + r;
        int col = bn + nbase + nb * 16 + (l & 15);
        Cv[(size_t)row * NQKV + col] = f2bf(acc[mb][nb][r] + bias[col]);
      }
    }
  }
}

// ---------------- output GEMM: C = AO @ (W_hi + W_lo)^T + bias, fp32 out -------
// A shared between both B segments: stage As once + Bh + Bl, 64 MFMA/barrier-pair.
__global__ __launch_bounds__(256)
void gemm_out(const unsigned short* __restrict__ A,    // [4096][2048] bf16
              const unsigned short* __restrict__ BT,   // [2048][4096] hi|lo
              const float* __restrict__ bias,
              float* __restrict__ C) {
  __shared__ unsigned short As[128 * 64];
  __shared__ unsigned short Bh[128 * 64];
  __shared__ unsigned short Bl[128 * 64];
  const int tid = threadIdx.x;
  const int w = tid >> 6, l = tid & 63;
  const int bm = blockIdx.y * 128, bn = blockIdx.x * 128;
  const int mbase = (w & 1) * 64, nbase = (w >> 1) * 64;

  f32x4 acc[4][4] = {};

  for (int t = 0; t < 32; ++t) {
    const int k = t * 64;
    __syncthreads();
#pragma unroll
    for (int i = 0; i < 4; ++i) {
      int r0 = w * 32 + i * 8;
      int row = r0 + (l >> 3);
      int gr = l & 7;
      int swz = (gr ^ (row & 7)) << 3;
      GLOAD16(A + (size_t)(bm + row) * 2048 + k + swz, As + r0 * 64);
      GLOAD16(BT + (size_t)(bn + row) * 4096 + k + swz, Bh + r0 * 64);
      GLOAD16(BT + (size_t)(bn + row) * 4096 + 2048 + k + swz, Bl + r0 * 64);
    }
    __syncthreads();
#pragma unroll
    for (int ks = 0; ks < 2; ++ks) {
      bf16x8 af[4], bfr[4];
#pragma unroll
      for (int mb = 0; mb < 4; ++mb) {
        int row = mbase + mb * 16 + (l & 15);
        int g = ks * 4 + (l >> 4);
        af[mb] = *(const bf16x8*)((const char*)As + row * 128 + ((g ^ (row & 7)) << 4));
      }
#pragma unroll
      for (int nb = 0; nb < 4; ++nb) {
        int row = nbase + nb * 16 + (l & 15);
        int g = ks * 4 + (l >> 4);
        bfr[nb] = *(const bf16x8*)((const char*)Bh + row * 128 + ((g ^ (row & 7)) << 4));
      }
#pragma unroll
      for (int mb = 0; mb < 4; ++mb)
#pragma unroll
        for (int nb = 0; nb < 4; ++nb)
          acc[mb][nb] = MFMA16x16x32(af[mb], bfr[nb], acc[mb][nb], 0, 0, 0);
#pragma unroll
      for (int nb = 0; nb < 4; ++nb) {
        int row = nbase + nb * 16 + (l & 15);
        int g = ks * 4 + (l >> 4);
        bfr[nb] = *(const bf16x8*)((const char*)Bl + row * 128 + ((g ^ (row & 7)) << 4));
      }
#pragma unroll
      for (int mb = 0; mb < 4; ++mb)
#pragma unroll
        for (int nb = 0; nb < 4; ++nb)
          acc[mb][nb] = MFMA16x16x32(af[mb], bfr[nb], acc[mb][nb], 0, 0, 0);
    }
  }

#pragma unroll
  for (int mb = 0; mb < 4; ++mb) {
#pragma unroll
    for (int nb = 0; nb < 4; ++nb) {
#pragma unroll
      for (int r = 0; r < 4; ++r) {
        int row = bm + mbase + mb * 16 + (l >> 4) * 4 + r;
        int col = bn + nbase + nb * 16 + (l & 15);
        C[(size_t)row * 2048 + col] = acc[mb][nb][r] + bias[col];
      }
    }
  }
}

// ---------------- MFMA flash attention (swapped-QK^T, K/V double-buffered) ------
// grid (SS/128, B*16). 4 waves; wave w owns q-rows [w*32, w*32+32) (2 m-blocks).
// K/V ping-pong LDS buffers; next tile's 8 gload_lds stay in flight across the
// compute phase (counted vmcnt(8), raw s_barrier; no vmcnt(0) drain in loop).
__global__ __launch_bounds__(256, 2)
void attn_mfma(const unsigned short* __restrict__ QKV,
               const unsigned short* __restrict__ VT,
               unsigned short* __restrict__ AOp) {
  __shared__ unsigned short Ks[2][64 * 128];    // [key][d]   2x16KB
  __shared__ unsigned short VsT[2][128 * 64];   // [d][key]   2x16KB
  __shared__ unsigned short Ps[4 * 32 * 64];    // per-wave P 16KB
  const int tid = threadIdx.x;
  const int w = tid >> 6, l = tid & 63;
  const int qt = blockIdx.x;
  const int bh = blockIdx.y;
  const int b = bh >> 4, h = bh & 15, g = h >> 2;
  const int lg = l >> 4;         // lane group 0..3
  const int lr16 = l & 15;       // lane row within 16

  bf16x8 qf[2][4];
#pragma unroll
  for (int mb = 0; mb < 2; ++mb) {
    const int qrow = b * SS + qt * 128 + w * 32 + mb * 16 + lr16;
    const unsigned short* qp = QKV + (size_t)qrow * NQKV + h * 128 + (lg << 3);
#pragma unroll
    for (int ks = 0; ks < 4; ++ks) qf[mb][ks] = *(const bf16x8*)(qp + ks * 32);
  }

  f32x4 oacc[2][8] = {};
  float mrow[2] = {-1e30f, -1e30f};   // running max (exp2 domain), row = l&15
  float lrow[2] = {0.f, 0.f};

  const unsigned short* kbase = QKV + (size_t)b * SS * NQKV + 2048 + g * 128;
  const unsigned short* vtbase = VT + (size_t)(b * 4 + g) * 128 * 2048;
  char* pw = (char*)Ps + w * 4096;

#define STAGE_KV(buf, ktile) do { \
    _Pragma("unroll") \
    for (int i = 0; i < 4; ++i) { \
      int r0 = w * 16 + i * 4; \
      int row = r0 + (l >> 4); \
      int gr = l & 15; \
      GLOAD16(kbase + (size_t)((ktile) * 64 + row) * NQKV + ((gr ^ (row & 7)) << 3), \
              &Ks[buf][r0 * 128]); \
    } \
    _Pragma("unroll") \
    for (int i = 0; i < 4; ++i) { \
      int r0 = w * 32 + i * 8; \
      int row = r0 + (l >> 3); \
      int gr = l & 7; \
      GLOAD16(vtbase + (size_t)row * 2048 + (ktile) * 64 + ((gr ^ (row & 7)) << 3), \
              &VsT[buf][r0 * 64]); \
    } \
  } while (0)

  STAGE_KV(0, 0);
  int cur = 0;

  for (int kt = 0; kt < SS / 64; ++kt) {
    if (kt + 1 < SS / 64) {
      STAGE_KV(cur ^ 1, kt + 1);
      asm volatile("s_waitcnt vmcnt(8)" ::: "memory");   // current tile landed
    } else {
      asm volatile("s_waitcnt vmcnt(0)" ::: "memory");
    }
    __builtin_amdgcn_s_barrier();

    const unsigned short* Kc = Ks[cur];
    const unsigned short* Vc = VsT[cur];

    // QK^T (swapped): sacc[mb][nb] fragment of S^T:
    //   score[key = 16nb+4*lg+r][qrow = mb*16+lr16]
    f32x4 sacc[2][4] = {};
    __builtin_amdgcn_s_setprio(1);
#pragma unroll
    for (int ks = 0; ks < 4; ++ks) {
#pragma unroll
      for (int nb = 0; nb < 4; ++nb) {
        int key = nb * 16 + lr16;
        int grn = ks * 4 + lg;
        bf16x8 kf = *(const bf16x8*)((const char*)Kc + key * 256 + ((grn ^ (key & 7)) << 4));
#pragma unroll
        for (int mb = 0; mb < 2; ++mb)
          sacc[mb][nb] = MFMA16x16x32(kf, qf[mb][ks], sacc[mb][nb], 0, 0, 0);
      }
    }
    __builtin_amdgcn_s_setprio(0);

    // softmax (exp2 domain), defer-max, P^T quads -> LDS
    const int rowswz = (l & 7) << 4;
#pragma unroll
    for (int mb = 0; mb < 2; ++mb) {
      float nbm[4];
#pragma unroll
      for (int nb = 0; nb < 4; ++nb)
        nbm[nb] = fmaxf(fmaxf(sacc[mb][nb][0], sacc[mb][nb][1]),
                        fmaxf(sacc[mb][nb][2], sacc[mb][nb][3]));
      float pmax = fmaxf(fmaxf(nbm[0], nbm[1]), fmaxf(nbm[2], nbm[3]));
      pmax = fmaxf(pmax, __shfl_xor(pmax, 16, 64));
      pmax = fmaxf(pmax, __shfl_xor(pmax, 32, 64));
      if (__any(pmax > mrow[mb] + 11.5416f)) {   // 8 * log2e
        float mnew = fmaxf(mrow[mb], pmax);
        float alpha = __builtin_amdgcn_exp2f(mrow[mb] - mnew);
        lrow[mb] *= alpha;
        mrow[mb] = mnew;
        float av[4];
#pragma unroll
        for (int r = 0; r < 4; ++r) av[r] = __shfl(alpha, lg * 4 + r, 64);
#pragma unroll
        for (int db = 0; db < 8; ++db) {
          oacc[mb][db][0] *= av[0]; oacc[mb][db][1] *= av[1];
          oacc[mb][db][2] *= av[2]; oacc[mb][db][3] *= av[3];
        }
      }
      float ssum = 0.f;
      char* pwm = pw + (mb * 16 + lr16) * 128;
#pragma unroll
      for (int nb = 0; nb < 4; ++nb) {
        float e0 = __builtin_amdgcn_exp2f(sacc[mb][nb][0] - mrow[mb]);
        float e1 = __builtin_amdgcn_exp2f(sacc[mb][nb][1] - mrow[mb]);
        float e2 = __builtin_amdgcn_exp2f(sacc[mb][nb][2] - mrow[mb]);
        float e3 = __builtin_amdgcn_exp2f(sacc[mb][nb][3] - mrow[mb]);
        ssum += (e0 + e1) + (e2 + e3);
        uint32_t p01, p23;
        asm("v_cvt_pk_bf16_f32 %0, %1, %2" : "=v"(p01) : "v"(e0), "v"(e1));
        asm("v_cvt_pk_bf16_f32 %0, %1, %2" : "=v"(p23) : "v"(e2), "v"(e3));
        uint2 q; q.x = p01; q.y = p23;
        *(uint2*)(pwm + ((((nb << 2) + lg) << 3) ^ rowswz)) = q;
      }
      ssum += __shfl_xor(ssum, 16, 64);
      ssum += __shfl_xor(ssum, 32, 64);
      lrow[mb] += ssum;
    }

    // PV: O(32x128) += P(32x64) @ V(64x128)
    __builtin_amdgcn_s_setprio(1);
#pragma unroll
    for (int ks = 0; ks < 2; ++ks) {
      int grn = ks * 4 + lg;
      bf16x8 pf[2];
#pragma unroll
      for (int mb = 0; mb < 2; ++mb) {
        int prow = mb * 16 + lr16;
        pf[mb] = *(const bf16x8*)(pw + prow * 128 + ((grn ^ (prow & 7)) << 4));
      }
#pragma unroll
      for (int nb = 0; nb < 8; ++nb) {
        int d = nb * 16 + lr16;
        bf16x8 vf = *(const bf16x8*)((const char*)Vc + d * 128 + ((grn ^ (d & 7)) << 4));
#pragma unroll
        for (int mb = 0; mb < 2; ++mb)
          oacc[mb][nb] = MFMA16x16x32(pf[mb], vf, oacc[mb][nb], 0, 0, 0);
      }
    }
    __builtin_amdgcn_s_setprio(0);

    __builtin_amdgcn_s_barrier();   // protect buf[cur] before next-iter staging
    cur ^= 1;
  }
#undef STAGE_KV

  // epilogue: AO (bf16 hi only) [4096][2048]
#pragma unroll
  for (int mb = 0; mb < 2; ++mb) {
    const int rowb = b * SS + qt * 128 + w * 32 + mb * 16 + lg * 4;
#pragma unroll
    for (int r = 0; r < 4; ++r) {
      float rl = 1.0f / __shfl(lrow[mb], lg * 4 + r, 64);
      unsigned short* outp = AOp + (size_t)(rowb + r) * 2048 + h * 128 + lr16;
#pragma unroll
      for (int nb = 0; nb < 8; ++nb)
        outp[nb * 16] = f2bf(oacc[mb][nb][r] * rl);
    }
  }
}

extern "C" void kernel_launch(void* const* d_in, const int* in_sizes, int n_in,
                              void* d_out, int out_size, void* d_ws, size_t ws_size,
                              hipStream_t stream) {
  const float* x  = (const float*)d_in[0];
  const float* Wq = (const float*)d_in[1];
  const float* bq = (const float*)d_in[2];
  const float* Wk = (const float*)d_in[3];
  const float* bk = (const float*)d_in[4];
  const float* Wv = (const float*)d_in[5];
  const float* bv = (const float*)d_in[6];
  const float* Wo = (const float*)d_in[7];
  const float* bo = (const float*)d_in[8];
  float* out = (float*)d_out;

  char* ws = (char*)d_ws;
  unsigned short* x_bf  = (unsigned short*)(ws);              // 16.8 MB
  unsigned short* WqkvT = (unsigned short*)(ws + 16777216);   // 12.6 MB
  unsigned short* AO    = (unsigned short*)(ws);              // 16.8 MB (reuses x_bf)
  float*          bqkv  = (float*)(ws + 35651584);
  unsigned short* WoT   = (unsigned short*)(ws + 36700160);   // 16.8 MB
  unsigned short* QKV   = (unsigned short*)(ws + 54525952);   // 25.2 MB
  unsigned short* VT    = (unsigned short*)(ws + 79691776);   // 4.2 MB

  conv_x<<<4096, 256, 0, stream>>>(x, x_bf);
  pack_wqkvT<<<dim3(64, 96), 256, 0, stream>>>(Wq, Wk, Wv, WqkvT);
  pack_bias<<<12, 256, 0, stream>>>(bq, bk, bv, bqkv);
  pack_woT<<<dim3(64, 64), 256, 0, stream>>>(Wo, WoT);
  gemm_qkv<<<dim3(24, 32), 256, 0, stream>>>(x_bf, WqkvT, bqkv, QKV, VT);
  attn_mfma<<<dim3(16, 32), 256, 0, stream>>>(QKV, VT, AO);
  gemm_out<<<dim3(16, 32), 256, 0, stream>>>(AO, WoT, bo, out);
}

// Round 6
// 225.754 us; speedup vs baseline: 12.0917x; 1.1169x over previous
//
#include <hip/hip_runtime.h>
#include <math.h>
#include <stdint.h>

#define D_MODEL 2048
#define SS 2048
#define BB 2
#define ROWS (BB*SS)      // 4096
#define NQKV 3072

typedef __attribute__((ext_vector_type(8))) short bf16x8;
typedef __attribute__((ext_vector_type(4))) float f32x4;
typedef __attribute__((ext_vector_type(16))) float f32x16;
typedef __attribute__((ext_vector_type(4))) unsigned int u32x4;
typedef __attribute__((ext_vector_type(8))) unsigned short ushort8v;
typedef __attribute__((ext_vector_type(4))) unsigned short ushort4v;

// scale(1/sqrt(128)) * log2(e): folded into Wk/bk so QK^T scores are exp2-domain
#define KSCALE 0.12751879566649053f

__device__ __forceinline__ unsigned short f2bf(float f) {
  uint32_t u = __builtin_bit_cast(uint32_t, f);
  return (unsigned short)((u + 0x7FFFu + ((u >> 16) & 1u)) >> 16);
}

#define MFMA16x16x32 __builtin_amdgcn_mfma_f32_16x16x32_bf16
#define MFMA32x32x16 __builtin_amdgcn_mfma_f32_32x32x16_bf16

#define GLOAD16(gsrc, ldst) \
  __builtin_amdgcn_global_load_lds((const __attribute__((address_space(1))) void*)(gsrc), \
      (__attribute__((address_space(3))) void*)(ldst), 16, 0, 0)

// ---------------- fp32 -> bf16 convert (x) ----------------
__global__ __launch_bounds__(256)
void conv_x(const float* __restrict__ x, unsigned short* __restrict__ xb) {
  size_t i = ((size_t)blockIdx.x * 256 + threadIdx.x) * 8;
  float4 v0 = *(const float4*)(x + i);
  float4 v1 = *(const float4*)(x + i + 4);
  ushort8v o;
  o[0]=f2bf(v0.x); o[1]=f2bf(v0.y); o[2]=f2bf(v0.z); o[3]=f2bf(v0.w);
  o[4]=f2bf(v1.x); o[5]=f2bf(v1.y); o[6]=f2bf(v1.z); o[7]=f2bf(v1.w);
  *(ushort8v*)(xb + i) = o;
}

// ---------------- pack Wq|Wk|Wv transposed -> WT[3072][2048] bf16 ----------------
__global__ __launch_bounds__(256)
void pack_wqkvT(const float* __restrict__ Wq, const float* __restrict__ Wk,
                const float* __restrict__ Wv, unsigned short* __restrict__ WT) {
  __shared__ float T[32][33];
  const int k0 = blockIdx.x * 32, n0 = blockIdx.y * 32;
  const int tid = threadIdx.x;
  const float* W; int nbase, stride; float fac = 1.0f;
  if (n0 < 2048)      { W = Wq; nbase = n0;        stride = 2048; }
  else if (n0 < 2560) { W = Wk; nbase = n0 - 2048; stride = 512; fac = KSCALE; }
  else                { W = Wv; nbase = n0 - 2560; stride = 512;  }
  int r = tid >> 3, c = (tid & 7) * 4;
  float4 v = *(const float4*)(W + (size_t)(k0 + r) * stride + nbase + c);
  T[c + 0][r] = v.x; T[c + 1][r] = v.y; T[c + 2][r] = v.z; T[c + 3][r] = v.w;
  __syncthreads();
  ushort4v o;
  o[0]=f2bf(T[r][c]*fac); o[1]=f2bf(T[r][c+1]*fac);
  o[2]=f2bf(T[r][c+2]*fac); o[3]=f2bf(T[r][c+3]*fac);
  *(ushort4v*)(WT + (size_t)(n0 + r) * 2048 + k0 + c) = o;
}

// ---------------- pack Wo transposed -> WoT[2048][2048] bf16 (hi only) ----------
__global__ __launch_bounds__(256)
void pack_woT(const float* __restrict__ Wo, unsigned short* __restrict__ WoT) {
  __shared__ float T[32][33];
  const int k0 = blockIdx.x * 32, n0 = blockIdx.y * 32;
  const int tid = threadIdx.x;
  int r = tid >> 3, c = (tid & 7) * 4;
  float4 v = *(const float4*)(Wo + (size_t)(k0 + r) * 2048 + n0 + c);
  T[c+0][r]=v.x; T[c+1][r]=v.y; T[c+2][r]=v.z; T[c+3][r]=v.w;
  __syncthreads();
  ushort4v o;
#pragma unroll
  for (int j = 0; j < 4; ++j) o[j] = f2bf(T[r][c + j]);
  *(ushort4v*)(WoT + (size_t)(n0 + r) * 2048 + k0 + c) = o;
}

__global__ void pack_bias(const float* __restrict__ bq, const float* __restrict__ bk,
                          const float* __restrict__ bv, float* __restrict__ bqkv) {
  int i = blockIdx.x * 256 + threadIdx.x;
  if (i >= 3072) return;
  bqkv[i] = i < 2048 ? bq[i]
          : (i < 2560 ? bk[i - 2048] * KSCALE : bv[i - 2560]);
}

// ---------------- bf16 MFMA GEMM (QKV projection) ----------------
__global__ __launch_bounds__(256)
void gemm_qkv(const unsigned short* __restrict__ A,
              const unsigned short* __restrict__ BT,
              const float* __restrict__ bias,
              unsigned short* __restrict__ Cv,
              unsigned short* __restrict__ VTp) {
  __shared__ unsigned short As[128 * 64];
  __shared__ unsigned short Bs[128 * 64];
  const int tid = threadIdx.x;
  const int w = tid >> 6, l = tid & 63;
  const int bm = blockIdx.y * 128, bn = blockIdx.x * 128;
  const int mbase = (w & 1) * 64, nbase = (w >> 1) * 64;

  f32x4 acc[4][4] = {};

  for (int t = 0; t < 32; ++t) {
    const int k = t * 64;
    __syncthreads();
#pragma unroll
    for (int i = 0; i < 4; ++i) {
      int r0 = w * 32 + i * 8;
      int row = r0 + (l >> 3);
      int gr = l & 7;
      GLOAD16(A + (size_t)(bm + row) * 2048 + k + ((gr ^ (row & 7)) << 3), As + r0 * 64);
      GLOAD16(BT + (size_t)(bn + row) * 2048 + k + ((gr ^ (row & 7)) << 3), Bs + r0 * 64);
    }
    __syncthreads();
#pragma unroll
    for (int ks = 0; ks < 2; ++ks) {
      bf16x8 af[4], bfr[4];
#pragma unroll
      for (int mb = 0; mb < 4; ++mb) {
        int row = mbase + mb * 16 + (l & 15);
        int g = ks * 4 + (l >> 4);
        af[mb] = *(const bf16x8*)((const char*)As + row * 128 + ((g ^ (row & 7)) << 4));
      }
#pragma unroll
      for (int nb = 0; nb < 4; ++nb) {
        int row = nbase + nb * 16 + (l & 15);
        int g = ks * 4 + (l >> 4);
        bfr[nb] = *(const bf16x8*)((const char*)Bs + row * 128 + ((g ^ (row & 7)) << 4));
      }
#pragma unroll
      for (int mb = 0; mb < 4; ++mb)
#pragma unroll
        for (int nb = 0; nb < 4; ++nb)
          acc[mb][nb] = MFMA16x16x32(af[mb], bfr[nb], acc[mb][nb], 0, 0, 0);
    }
  }

  if (bn >= 2560) {
    // V tile: write transposed VT[(b*512 + (col-2560))][token]
#pragma unroll
    for (int mb = 0; mb < 4; ++mb) {
      int row0 = bm + mbase + mb * 16 + (l >> 4) * 4;
      int bidx = row0 >> 11, tok = row0 & 2047;
#pragma unroll
      for (int nb = 0; nb < 4; ++nb) {
        int col = bn + nbase + nb * 16 + (l & 15);
        ushort4v o;
#pragma unroll
        for (int r = 0; r < 4; ++r) o[r] = f2bf(acc[mb][nb][r] + bias[col]);
        *(ushort4v*)(VTp + ((size_t)(bidx * 512 + col - 2560)) * 2048 + tok) = o;
      }
    }
    return;
  }
#pragma unroll
  for (int mb = 0; mb < 4; ++mb) {
#pragma unroll
    for (int nb = 0; nb < 4; ++nb) {
#pragma unroll
      for (int r = 0; r < 4; ++r) {
        int row = bm + mbase + mb * 16 + (l >> 4) * 4 + r;
        int col = bn + nbase + nb * 16 + (l & 15);
        Cv[(size_t)row * NQKV + col] = f2bf(acc[mb][nb][r] + bias[col]);
      }
    }
  }
}

// ---------------- output GEMM: C = AO @ WoT^T + bias, fp32 out ----------------
__global__ __launch_bounds__(256)
void gemm_out(const unsigned short* __restrict__ A,    // [4096][2048] bf16
              const unsigned short* __restrict__ BT,   // [2048][2048] bf16
              const float* __restrict__ bias,
              float* __restrict__ C) {
  __shared__ unsigned short As[128 * 64];
  __shared__ unsigned short Bs[128 * 64];
  const int tid = threadIdx.x;
  const int w = tid >> 6, l = tid & 63;
  const int bm = blockIdx.y * 128, bn = blockIdx.x * 128;
  const int mbase = (w & 1) * 64, nbase = (w >> 1) * 64;

  f32x4 acc[4][4] = {};

  for (int t = 0; t < 32; ++t) {
    const int k = t * 64;
    __syncthreads();
#pragma unroll
    for (int i = 0; i < 4; ++i) {
      int r0 = w * 32 + i * 8;
      int row = r0 + (l >> 3);
      int gr = l & 7;
      GLOAD16(A + (size_t)(bm + row) * 2048 + k + ((gr ^ (row & 7)) << 3), As + r0 * 64);
      GLOAD16(BT + (size_t)(bn + row) * 2048 + k + ((gr ^ (row & 7)) << 3), Bs + r0 * 64);
    }
    __syncthreads();
#pragma unroll
    for (int ks = 0; ks < 2; ++ks) {
      bf16x8 af[4], bfr[4];
#pragma unroll
      for (int mb = 0; mb < 4; ++mb) {
        int row = mbase + mb * 16 + (l & 15);
        int g = ks * 4 + (l >> 4);
        af[mb] = *(const bf16x8*)((const char*)As + row * 128 + ((g ^ (row & 7)) << 4));
      }
#pragma unroll
      for (int nb = 0; nb < 4; ++nb) {
        int row = nbase + nb * 16 + (l & 15);
        int g = ks * 4 + (l >> 4);
        bfr[nb] = *(const bf16x8*)((const char*)Bs + row * 128 + ((g ^ (row & 7)) << 4));
      }
#pragma unroll
      for (int mb = 0; mb < 4; ++mb)
#pragma unroll
        for (int nb = 0; nb < 4; ++nb)
          acc[mb][nb] = MFMA16x16x32(af[mb], bfr[nb], acc[mb][nb], 0, 0, 0);
    }
  }

#pragma unroll
  for (int mb = 0; mb < 4; ++mb) {
#pragma unroll
    for (int nb = 0; nb < 4; ++nb) {
#pragma unroll
      for (int r = 0; r < 4; ++r) {
        int row = bm + mbase + mb * 16 + (l >> 4) * 4 + r;
        int col = bn + nbase + nb * 16 + (l & 15);
        C[(size_t)row * 2048 + col] = acc[mb][nb][r] + bias[col];
      }
    }
  }
}

// ---------------- MFMA flash attention: 32x32 fragments, in-register P --------
// grid (SS/128, B*16). 4 waves; wave w owns q-rows [w*32, w*32+32).
// S^T = mfma32(K,Q): lane owns q-row q=l&31, 32 in-lane scores (2 kb x 16 regs,
//   key = 32kb + (r&3)+8(r>>2)+4h, h=l>>5).
// P^T built in-register (cvt_pk + 2 shfl_xor(32) per kstep).
// O^T = mfma32(V^T, P^T): lane owns col q=l&31 -> rescale/normalize lane-local.
__global__ __launch_bounds__(256, 2)
void attn_mfma(const unsigned short* __restrict__ QKV,
               const unsigned short* __restrict__ VT,
               unsigned short* __restrict__ AOp) {
  __shared__ unsigned short Ks[2][64 * 128];    // [key][d]   2x16KB
  __shared__ unsigned short VsT[2][128 * 64];   // [d][key]   2x16KB
  const int tid = threadIdx.x;
  const int w = tid >> 6, l = tid & 63;
  const int qt = blockIdx.x;
  const int bh = blockIdx.y;
  const int b = bh >> 4, hh = bh & 15, g = hh >> 2;
  const int h = l >> 5;      // k-group half
  const int q = l & 31;      // owned q-row / output column

  // Q fragments (B-operand): lane holds Q[q][k = 16*kk + 8h + j]
  bf16x8 qf[8];
  {
    const int qrow = b * SS + qt * 128 + w * 32 + q;
    const unsigned short* qp = QKV + (size_t)qrow * NQKV + hh * 128 + h * 8;
#pragma unroll
    for (int kk = 0; kk < 8; ++kk) qf[kk] = *(const bf16x8*)(qp + kk * 16);
  }

  f32x16 oaccT[4] = {};      // O^T[d = 32db + (r&3)+8(r>>2)+4h][q]
  float mrow = -1e30f, lrow = 0.f;

  const unsigned short* kbase = QKV + (size_t)b * SS * NQKV + 2048 + g * 128;
  const unsigned short* vtbase = VT + (size_t)(b * 4 + g) * 128 * 2048;

#define STAGE_KV(buf, ktile) do { \
    _Pragma("unroll") \
    for (int i = 0; i < 4; ++i) { \
      int r0 = w * 16 + i * 4; \
      int row = r0 + (l >> 4); \
      int gr = l & 15; \
      GLOAD16(kbase + (size_t)((ktile) * 64 + row) * NQKV + ((gr ^ (row & 15)) << 3), \
              &Ks[buf][r0 * 128]); \
    } \
    _Pragma("unroll") \
    for (int i = 0; i < 4; ++i) { \
      int r0 = w * 32 + i * 8; \
      int row = r0 + (l >> 3); \
      int gr = l & 7; \
      GLOAD16(vtbase + (size_t)row * 2048 + (ktile) * 64 + ((gr ^ (row & 7)) << 3), \
              &VsT[buf][r0 * 64]); \
    } \
  } while (0)

  STAGE_KV(0, 0);
  int cur = 0;

  for (int kt = 0; kt < SS / 64; ++kt) {
    if (kt + 1 < SS / 64) {
      STAGE_KV(cur ^ 1, kt + 1);
      asm volatile("s_waitcnt vmcnt(8)" ::: "memory");
    } else {
      asm volatile("s_waitcnt vmcnt(0)" ::: "memory");
    }
    __builtin_amdgcn_s_barrier();

    const unsigned short* Kc = Ks[cur];
    const unsigned short* Vc = VsT[cur];

    // QK^T: sacc[kb] = S^T tile (keys 32kb..32kb+31) x (q 0..31)
    f32x16 sacc[2] = {};
    __builtin_amdgcn_s_setprio(1);
#pragma unroll
    for (int kk = 0; kk < 8; ++kk) {
#pragma unroll
      for (int kb = 0; kb < 2; ++kb) {
        int key = kb * 32 + q;
        bf16x8 kf = *(const bf16x8*)((const char*)Kc + key * 256
                                     + (((kk * 2 + h) ^ (key & 15)) << 4));
        sacc[kb] = MFMA32x32x16(kf, qf[kk], sacc[kb], 0, 0, 0);
      }
    }
    __builtin_amdgcn_s_setprio(0);

    // softmax (exp2 domain): row q's 64 scores split across lane pair (l, l^32)
    float pmax = sacc[0][0];
#pragma unroll
    for (int r = 1; r < 16; ++r) pmax = fmaxf(pmax, sacc[0][r]);
#pragma unroll
    for (int r = 0; r < 16; ++r) pmax = fmaxf(pmax, sacc[1][r]);
    pmax = fmaxf(pmax, __shfl_xor(pmax, 32, 64));
    if (__any(pmax > mrow + 11.5416f)) {   // defer-max, THR = 8*log2e
      float mnew = fmaxf(mrow, pmax);
      float alpha = __builtin_amdgcn_exp2f(mrow - mnew);
      lrow *= alpha;
      mrow = mnew;
#pragma unroll
      for (int db = 0; db < 4; ++db)
#pragma unroll
        for (int r = 0; r < 16; ++r) oaccT[db][r] *= alpha;
    }
    float e[2][16];
    float ssum = 0.f;
#pragma unroll
    for (int kb = 0; kb < 2; ++kb)
#pragma unroll
      for (int r = 0; r < 16; ++r) {
        e[kb][r] = __builtin_amdgcn_exp2f(sacc[kb][r] - mrow);
        ssum += e[kb][r];
      }
    ssum += __shfl_xor(ssum, 32, 64);
    lrow += ssum;

    // P^T B-fragments in-register: pf[ks][j] = P[q][key = 16ks + 8h + j]
    bf16x8 pf[4];
#pragma unroll
    for (int ks = 0; ks < 4; ++ks) {
      const int kb = ks >> 1, r0 = (ks & 1) * 8;
      uint32_t w0, w1, w2, w3;
      asm("v_cvt_pk_bf16_f32 %0, %1, %2" : "=v"(w0) : "v"(e[kb][r0+0]), "v"(e[kb][r0+1]));
      asm("v_cvt_pk_bf16_f32 %0, %1, %2" : "=v"(w1) : "v"(e[kb][r0+2]), "v"(e[kb][r0+3]));
      asm("v_cvt_pk_bf16_f32 %0, %1, %2" : "=v"(w2) : "v"(e[kb][r0+4]), "v"(e[kb][r0+5]));
      asm("v_cvt_pk_bf16_f32 %0, %1, %2" : "=v"(w3) : "v"(e[kb][r0+6]), "v"(e[kb][r0+7]));
      uint32_t s1 = h ? w0 : w2;             // send partner what it needs
      uint32_t s2 = h ? w1 : w3;
      uint32_t r1 = __shfl_xor((int)s1, 32, 64);
      uint32_t r2 = __shfl_xor((int)s2, 32, 64);
      u32x4 u;
      u[0] = h ? r1 : w0;
      u[1] = h ? r2 : w1;
      u[2] = h ? w2 : r1;
      u[3] = h ? w3 : r2;
      pf[ks] = __builtin_bit_cast(bf16x8, u);
    }

    // PV: O^T[d][q] += V^T[d][key] @ P^T[key][q]
    __builtin_amdgcn_s_setprio(1);
#pragma unroll
    for (int ks = 0; ks < 4; ++ks) {
#pragma unroll
      for (int db = 0; db < 4; ++db) {
        int d = db * 32 + q;
        bf16x8 vf = *(const bf16x8*)((const char*)Vc + d * 128
                                     + (((ks * 2 + h) ^ (d & 7)) << 4));
        oaccT[db] = MFMA32x32x16(vf, pf[ks], oaccT[db], 0, 0, 0);
      }
    }
    __builtin_amdgcn_s_setprio(0);

    __builtin_amdgcn_s_barrier();
    cur ^= 1;
  }
#undef STAGE_KV

  // epilogue: normalize (lane-local), bounce O^T -> O via LDS, coalesced store
  float rl = 1.0f / lrow;
  char* lbase = (char*)Ks + w * 8192;   // 32 rows x 256B per wave
#pragma unroll
  for (int db = 0; db < 4; ++db) {
#pragma unroll
    for (int r = 0; r < 16; r += 2) {
      float f0 = oaccT[db][r] * rl, f1 = oaccT[db][r + 1] * rl;
      uint32_t pk2;
      asm("v_cvt_pk_bf16_f32 %0, %1, %2" : "=v"(pk2) : "v"(f0), "v"(f1));
      int slot = db * 4 + (r >> 2);
      int phys = slot ^ q;               // q = l&31; slot 4 bits -> use q&15
      phys = (slot ^ (q & 15));
      *(uint32_t*)(lbase + q * 256 + phys * 16 + 8 * h + 2 * (r & 3)) = pk2;
    }
  }
#pragma unroll
  for (int i = 0; i < 8; ++i) {
    int row = i * 4 + (l >> 4);
    int slot = l & 15;
    int phys = slot ^ (row & 15);
    u32x4 vv = *(const u32x4*)(lbase + row * 256 + phys * 16);
    *(u32x4*)(AOp + (size_t)(b * SS + qt * 128 + w * 32 + row) * 2048
              + hh * 128 + slot * 8) = vv;
  }
}

extern "C" void kernel_launch(void* const* d_in, const int* in_sizes, int n_in,
                              void* d_out, int out_size, void* d_ws, size_t ws_size,
                              hipStream_t stream) {
  const float* x  = (const float*)d_in[0];
  const float* Wq = (const float*)d_in[1];
  const float* bq = (const float*)d_in[2];
  const float* Wk = (const float*)d_in[3];
  const float* bk = (const float*)d_in[4];
  const float* Wv = (const float*)d_in[5];
  const float* bv = (const float*)d_in[6];
  const float* Wo = (const float*)d_in[7];
  const float* bo = (const float*)d_in[8];
  float* out = (float*)d_out;

  char* ws = (char*)d_ws;
  unsigned short* x_bf  = (unsigned short*)(ws);              // 16.8 MB
  unsigned short* WqkvT = (unsigned short*)(ws + 16777216);   // 12.6 MB
  unsigned short* AO    = (unsigned short*)(ws);              // 16.8 MB (reuses x_bf)
  float*          bqkv  = (float*)(ws + 35651584);
  unsigned short* WoT   = (unsigned short*)(ws + 36700160);   // 8.4 MB
  unsigned short* QKV   = (unsigned short*)(ws + 54525952);   // 25.2 MB
  unsigned short* VT    = (unsigned short*)(ws + 79691776);   // 4.2 MB

  conv_x<<<4096, 256, 0, stream>>>(x, x_bf);
  pack_wqkvT<<<dim3(64, 96), 256, 0, stream>>>(Wq, Wk, Wv, WqkvT);
  pack_bias<<<12, 256, 0, stream>>>(bq, bk, bv, bqkv);
  pack_woT<<<dim3(64, 64), 256, 0, stream>>>(Wo, WoT);
  gemm_qkv<<<dim3(24, 32), 256, 0, stream>>>(x_bf, WqkvT, bqkv, QKV, VT);
  attn_mfma<<<dim3(16, 32), 256, 0, stream>>>(QKV, VT, AO);
  gemm_out<<<dim3(16, 32), 256, 0, stream>>>(AO, WoT, bo, out);
}